// Round 13
// baseline (227.020 us; speedup 1.0000x reference)
//
#include <hip/hip_runtime.h>
#include <hip/hip_fp16.h>

// ConformalGCN: 2-layer GCN, N=100000, E=1600000 (+self loops).
// R12: gemm1 rebuilt OFF the LDS pipe (R10/11 were ds_read-throughput-bound,
//      ~47us model == 44.8us measured): W1 column in 64 VGPRs per lane,
//      x row word broadcast via static readlane, inner loop = pure VALU
//      (4 readlane + 4 dot2 per k2). csr_agg/gemm2/CSR build = R10.

#define IN_F  128
#define HID_F 64
#define OUT_F 96
#define CHUNK 4096
#define MAXB  12288         // stage capacity (padded bucket size), 48 KiB
#define AGG_BLOCKS 4096
#define ONE_LO 0x00003C00u  // fp16 (1.0, 0.0)
#define ONE_HI 0x3C000000u  // fp16 (0.0, 1.0)

typedef _Float16 f16x2 __attribute__((ext_vector_type(2)));

__device__ __forceinline__ float2 unpack2(unsigned u) {
    __half2 h = *reinterpret_cast<__half2*>(&u);
    return __half22float2(h);
}
__device__ __forceinline__ unsigned f2h2(float lo, float hi) {
    __half2 h = __floats2half2_rn(lo, hi);
    return *reinterpret_cast<unsigned*>(&h);
}

#if defined(__has_builtin)
#if __has_builtin(__builtin_amdgcn_fdot2)
#define HAS_FDOT2 1
#endif
#if __has_builtin(__builtin_amdgcn_readlane)
#define HAS_RDLANE 1
#endif
#endif
#ifndef HAS_FDOT2
#define HAS_FDOT2 0
#endif
#ifndef HAS_RDLANE
#define HAS_RDLANE 0
#endif

__device__ __forceinline__ float fdot2u(unsigned a, unsigned b, float c) {
#if HAS_FDOT2
    return __builtin_amdgcn_fdot2(__builtin_bit_cast(f16x2, a),
                                  __builtin_bit_cast(f16x2, b), c, false);
#else
    float2 fa = unpack2(a), fb = unpack2(b);
    return fmaf(fa.y, fb.y, fmaf(fa.x, fb.x, c));
#endif
}

__device__ __forceinline__ unsigned bcast_lane(unsigned v, int srclane) {
#if HAS_RDLANE
    return (unsigned)__builtin_amdgcn_readlane((int)v, srclane);
#else
    return (unsigned)__shfl((int)v, srclane, 64);
#endif
}

// zero the sentinel feature rows hs[n], hs2[n]
__global__ __launch_bounds__(64) void init_sentinel(unsigned* __restrict__ hs,
                                                    unsigned* __restrict__ hs2, int n) {
    int t = threadIdx.x;
    if (t < 32) {
        hs[(size_t)n * 32 + t] = 0u;
        hs2[(size_t)n * 32 + t] = 0u;
    }
}

// ---- pass 1a: per-chunk bucket histograms (bucket-major layout) ----
__global__ __launch_bounds__(256) void hist_chunks(const int* __restrict__ dst,
                                                   int* __restrict__ hist,
                                                   int E, int nbuck, int nchunk) {
    __shared__ int cnt[512];
    for (int i = threadIdx.x; i < nbuck; i += 256) cnt[i] = 0;
    __syncthreads();
    const int base = blockIdx.x * CHUNK;
    const int lim = min(base + CHUNK, E);
    for (int e = base + threadIdx.x; e < lim; e += 256)
        atomicAdd(&cnt[dst[e] >> 8], 1);
    __syncthreads();
    for (int b = threadIdx.x; b < nbuck; b += 256)
        hist[b * nchunk + blockIdx.x] = cnt[b];
}

// ---- hierarchical exclusive prefix sum (1024 elems/block) ----
__global__ __launch_bounds__(256) void scan_blocks(const int* __restrict__ in,
                                                   int* __restrict__ pre,
                                                   int* __restrict__ bsum, int m) {
    __shared__ int lds[256];
    const int t = threadIdx.x;
    const int base = blockIdx.x * 1024 + t * 4;
    int v0 = (base + 0 < m) ? in[base + 0] : 0;
    int v1 = (base + 1 < m) ? in[base + 1] : 0;
    int v2 = (base + 2 < m) ? in[base + 2] : 0;
    int v3 = (base + 3 < m) ? in[base + 3] : 0;
    int s = v0 + v1 + v2 + v3;
    lds[t] = s;
    __syncthreads();
    for (int off = 1; off < 256; off <<= 1) {
        int add = (t >= off) ? lds[t - off] : 0;
        __syncthreads();
        lds[t] += add;
        __syncthreads();
    }
    int e = lds[t] - s;
    if (base + 0 < m) pre[base + 0] = e;
    e += v0;
    if (base + 1 < m) pre[base + 1] = e;
    e += v1;
    if (base + 2 < m) pre[base + 2] = e;
    e += v2;
    if (base + 3 < m) pre[base + 3] = e;
    if (t == 255) bsum[blockIdx.x] = lds[255];
}

__global__ __launch_bounds__(256) void scan_bsums(const int* __restrict__ bsum,
                                                  int* __restrict__ boffs, int nb) {
    __shared__ int lds[256];
    const int t = threadIdx.x;
    int v = (t < nb) ? bsum[t] : 0;
    lds[t] = v;
    __syncthreads();
    for (int off = 1; off < 256; off <<= 1) {
        int add = (t >= off) ? lds[t - off] : 0;
        __syncthreads();
        lds[t] += add;
        __syncthreads();
    }
    boffs[t] = lds[t] - v;
}

// ---- pass 1b: partition edges into bucket-grouped runs, 4B records ----
__global__ __launch_bounds__(256) void partition(const int* __restrict__ src,
                                                 const int* __restrict__ dst,
                                                 const int* __restrict__ offs,
                                                 const int* __restrict__ boffs,
                                                 unsigned* __restrict__ part,
                                                 int E, int nbuck, int nchunk) {
    __shared__ int off[512];
    for (int b = threadIdx.x; b < nbuck; b += 256) {
        int idx = b * nchunk + blockIdx.x;
        off[b] = offs[idx] + boffs[idx >> 10];
    }
    __syncthreads();
    const int base = blockIdx.x * CHUNK;
    const int lim = min(base + CHUNK, E);
    for (int e = base + threadIdx.x; e < lim; e += 256) {
        int d = dst[e], s = src[e];
        int pos = atomicAdd(&off[d >> 8], 1);
        part[pos] = ((unsigned)s << 8) | (unsigned)(d & 255);
    }
}

// ---- pass 2: per-bucket padded CSR finalize ----
__global__ __launch_bounds__(256) void build_bucket(const unsigned* __restrict__ part,
                                                    const int* __restrict__ offs,
                                                    const int* __restrict__ boffs,
                                                    int* __restrict__ csr_src,
                                                    int4* __restrict__ nodetab,
                                                    float* __restrict__ dinv,
                                                    int n, int E, int nbuck, int nchunk) {
    __shared__ int cnt[256], sc[256], off[256];
    __shared__ int stage[MAXB];
    const int b = blockIdx.x;
    const int t = threadIdx.x;
    const int i0 = b * nchunk;
    const int bstart = offs[i0] + boffs[i0 >> 10];
    int bend = E;
    if (b + 1 < nbuck) {
        const int i1 = (b + 1) * nchunk;
        bend = offs[i1] + boffs[i1 >> 10];
    }
    const int bstart_pad = bstart + b * 4096;
    const int nodebase = b << 8;
    const int nnodes = min(256, n - nodebase);

    cnt[t] = 0;
    __syncthreads();
    for (int i = bstart + t; i < bend; i += 256)
        atomicAdd(&cnt[part[i] & 255u], 1);
    __syncthreads();
    const int deg = cnt[t];
    const int pdeg = (deg + 15) & ~15;
    sc[t] = pdeg;
    __syncthreads();
    for (int o = 1; o < 256; o <<= 1) {
        int add = (t >= o) ? sc[t - o] : 0;
        __syncthreads();
        sc[t] += add;
        __syncthreads();
    }
    const int pexcl = sc[t] - pdeg;
    const int psize = sc[255];
    if (t < nnodes) {
        float dv = rsqrtf((float)(deg + 1));   // +1 self loop
        nodetab[nodebase + t] = make_int4(bstart_pad + pexcl,
                                          bstart_pad + pexcl + pdeg,
                                          __float_as_int(dv), 0);
        dinv[nodebase + t] = dv;
    }
    off[t] = pexcl;
    __syncthreads();

    if (psize <= MAXB) {
        for (int i = t; i < psize; i += 256) stage[i] = n;   // sentinel fill
        __syncthreads();
        for (int i = bstart + t; i < bend; i += 256) {
            unsigned r = part[i];
            int pos = atomicAdd(&off[r & 255u], 1);
            stage[pos] = (int)(r >> 8);
        }
        __syncthreads();
        for (int i = t; i < psize; i += 256)
            csr_src[bstart_pad + i] = stage[i];
    } else {   // safety fallback
        for (int i = t; i < psize; i += 256) csr_src[bstart_pad + i] = n;
        __syncthreads();
        for (int i = bstart + t; i < bend; i += 256) {
            unsigned r = part[i];
            int pos = atomicAdd(&off[r & 255u], 1);
            csr_src[bstart_pad + pos] = (int)(r >> 8);
        }
    }
}

// hs[row] = fp16x2( dinv[row] * (x[row] @ W1) ).  ZERO-LDS inner loop:
// lane l holds W1 column l packed in wreg[64] (coalesced 256B preloads,
// L2-hot) and word l of each of 4 rows; x broadcast via static readlane.
__global__ __launch_bounds__(256) void gemm1(const float* __restrict__ x,
                                             const float* __restrict__ W1,
                                             const float* __restrict__ dinv,
                                             unsigned* __restrict__ hs, int n) {
    const int lane = threadIdx.x & 63;
    const int wave = threadIdx.x >> 6;
    unsigned wreg[64];
#pragma unroll
    for (int k2 = 0; k2 < 64; ++k2)
        wreg[k2] = f2h2(W1[(2 * k2) * HID_F + lane],
                        W1[(2 * k2 + 1) * HID_F + lane]);
    const int nquad = (n + 3) >> 2;
    for (int q = blockIdx.x * 4 + wave; q < nquad; q += gridDim.x * 4) {
        const int r0 = q * 4;
        const bool h1 = r0 + 1 < n, h2 = r0 + 2 < n, h3 = r0 + 3 < n;
        const float* xp = x + (size_t)r0 * IN_F + lane * 2;
        float2 v0 = *(const float2*)(xp);
        float2 v1 = h1 ? *(const float2*)(xp + IN_F)     : make_float2(0.f, 0.f);
        float2 v2 = h2 ? *(const float2*)(xp + 2 * IN_F) : make_float2(0.f, 0.f);
        float2 v3 = h3 ? *(const float2*)(xp + 3 * IN_F) : make_float2(0.f, 0.f);
        unsigned x0 = f2h2(v0.x, v0.y);   // lane holds word `lane` of row r0+i
        unsigned x1 = f2h2(v1.x, v1.y);
        unsigned x2 = f2h2(v2.x, v2.y);
        unsigned x3 = f2h2(v3.x, v3.y);
        float a0 = 0.f, a1 = 0.f, a2 = 0.f, a3 = 0.f;
#pragma unroll
        for (int k2 = 0; k2 < 64; ++k2) {
            unsigned w = wreg[k2];
            a0 = fdot2u(bcast_lane(x0, k2), w, a0);
            a1 = fdot2u(bcast_lane(x1, k2), w, a1);
            a2 = fdot2u(bcast_lane(x2, k2), w, a2);
            a3 = fdot2u(bcast_lane(x3, k2), w, a3);
        }
        a0 *= dinv[r0];
        a1 *= h1 ? dinv[r0 + 1] : 0.f;
        a2 *= h2 ? dinv[r0 + 2] : 0.f;
        a3 *= h3 ? dinv[r0 + 3] : 0.f;
        float o0 = __shfl_xor(a0, 1), o1 = __shfl_xor(a1, 1);
        float o2 = __shfl_xor(a2, 1), o3 = __shfl_xor(a3, 1);
        if (!(lane & 1)) {
            int wd = lane >> 1;
            hs[(size_t)r0 * 32 + wd] = f2h2(a0, o0);
            if (h1) hs[(size_t)(r0 + 1) * 32 + wd] = f2h2(a1, o1);
            if (h2) hs[(size_t)(r0 + 2) * 32 + wd] = f2h2(a2, o2);
            if (h3) hs[(size_t)(r0 + 3) * 32 + wd] = f2h2(a3, o3);
        }
    }
}

// Grid-stride; each wave owns TWO consecutive nodes with interleaved
// branchless gather chains.  Rows padded to %16.  fdot2 lane-extract accum.
#define ACC2(u, slo, shi) { slo = fdot2u(u, ONE_LO, slo); shi = fdot2u(u, ONE_HI, shi); }
template <int LAYER>
__global__ __launch_bounds__(256) void csr_agg(const int4* __restrict__ nodetab,
                                               const int* __restrict__ csr_src,
                                               const unsigned* __restrict__ hs,
                                               const float* __restrict__ bias,
                                               unsigned* __restrict__ hout, int n) {
    const int lane = threadIdx.x & 63;
    const int g = lane >> 4;          // edge slot 0..3
    const int w = lane & 15;          // feats 4w..4w+3
    const unsigned* __restrict__ hw = hs + 2 * w;
    const int STR = gridDim.x * 8;
    const int SENT = n;

    int nodeA = (blockIdx.x * 4 + (threadIdx.x >> 6)) * 2;
    if (nodeA >= n) return;
    int4 ntA = nodetab[nodeA];
    bool hasB = nodeA + 1 < n;
    int4 ntB = hasB ? nodetab[nodeA + 1] : make_int4(0, 0, 0, 0);

    for (;;) {
        const int nxt = nodeA + STR;
        const bool more = nxt < n;
        int4 ntA_n, ntB_n;
        bool hasB_n = false;
        if (more) {
            ntA_n = nodetab[nxt];
            hasB_n = nxt + 1 < n;
            if (hasB_n) ntB_n = nodetab[nxt + 1];
        }

        int pA = ntA.x;
        const int endA = ntA.y;
        const float dnA = __int_as_float(ntA.z);
        int pB = hasB ? ntB.x : 0;
        const int endB = hasB ? ntB.y : 0;
        const float dnB = hasB ? __int_as_float(ntB.z) : 0.f;

        float aA0 = 0.f, aA1 = 0.f, aA2 = 0.f, aA3 = 0.f;
        float cA0 = 0.f, cA1 = 0.f, cA2 = 0.f, cA3 = 0.f;
        float aB0 = 0.f, aB1 = 0.f, aB2 = 0.f, aB3 = 0.f;
        float cB0 = 0.f, cB1 = 0.f, cB2 = 0.f, cB3 = 0.f;
        if (g == 0) {                                      // self loops, once
            uint2 suA = *(const uint2*)(hw + (size_t)nodeA * 32);
            ACC2(suA.x, aA0, aA1);
            ACC2(suA.y, aA2, aA3);
            if (hasB) {
                uint2 suB = *(const uint2*)(hw + (size_t)(nodeA + 1) * 32);
                ACC2(suB.x, aB0, aB1);
                ACC2(suB.y, aB2, aB3);
            }
        }
        while (pA < endA || pB < endB) {
            int4 ivA = (pA < endA) ? *(const int4*)&csr_src[pA + 4 * g]
                                   : make_int4(SENT, SENT, SENT, SENT);
            int4 ivB = (pB < endB) ? *(const int4*)&csr_src[pB + 4 * g]
                                   : make_int4(SENT, SENT, SENT, SENT);
            uint2 uA0 = *(const uint2*)(hw + (size_t)ivA.x * 32);
            uint2 uA1 = *(const uint2*)(hw + (size_t)ivA.y * 32);
            uint2 uA2 = *(const uint2*)(hw + (size_t)ivA.z * 32);
            uint2 uA3 = *(const uint2*)(hw + (size_t)ivA.w * 32);
            uint2 uB0 = *(const uint2*)(hw + (size_t)ivB.x * 32);
            uint2 uB1 = *(const uint2*)(hw + (size_t)ivB.y * 32);
            uint2 uB2 = *(const uint2*)(hw + (size_t)ivB.z * 32);
            uint2 uB3 = *(const uint2*)(hw + (size_t)ivB.w * 32);
            ACC2(uA0.x, aA0, aA1); ACC2(uA0.y, aA2, aA3);
            ACC2(uA1.x, cA0, cA1); ACC2(uA1.y, cA2, cA3);
            ACC2(uA2.x, aA0, aA1); ACC2(uA2.y, aA2, aA3);
            ACC2(uA3.x, cA0, cA1); ACC2(uA3.y, cA2, cA3);
            ACC2(uB0.x, aB0, aB1); ACC2(uB0.y, aB2, aB3);
            ACC2(uB1.x, cB0, cB1); ACC2(uB1.y, cB2, cB3);
            ACC2(uB2.x, aB0, aB1); ACC2(uB2.y, aB2, aB3);
            ACC2(uB3.x, cB0, cB1); ACC2(uB3.y, cB2, cB3);
            pA += 16; pB += 16;
        }
        aA0 += cA0; aA1 += cA1; aA2 += cA2; aA3 += cA3;
        aB0 += cB0; aB1 += cB1; aB2 += cB2; aB3 += cB3;
        aA0 += __shfl_xor(aA0, 16); aA0 += __shfl_xor(aA0, 32);
        aA1 += __shfl_xor(aA1, 16); aA1 += __shfl_xor(aA1, 32);
        aA2 += __shfl_xor(aA2, 16); aA2 += __shfl_xor(aA2, 32);
        aA3 += __shfl_xor(aA3, 16); aA3 += __shfl_xor(aA3, 32);
        aB0 += __shfl_xor(aB0, 16); aB0 += __shfl_xor(aB0, 32);
        aB1 += __shfl_xor(aB1, 16); aB1 += __shfl_xor(aB1, 32);
        aB2 += __shfl_xor(aB2, 16); aB2 += __shfl_xor(aB2, 32);
        aB3 += __shfl_xor(aB3, 16); aB3 += __shfl_xor(aB3, 32);

        if (g == 0) {
            float o0, o1, o2, o3;
            if (LAYER == 1) {
                float4 bb = *(const float4*)(bias + 4 * w);
                o0 = fmaxf(fmaf(dnA, aA0, bb.x), 0.f) * dnA;
                o1 = fmaxf(fmaf(dnA, aA1, bb.y), 0.f) * dnA;
                o2 = fmaxf(fmaf(dnA, aA2, bb.z), 0.f) * dnA;
                o3 = fmaxf(fmaf(dnA, aA3, bb.w), 0.f) * dnA;
            } else {
                o0 = dnA * aA0; o1 = dnA * aA1; o2 = dnA * aA2; o3 = dnA * aA3;
            }
            uint2 ov;
            ov.x = f2h2(o0, o1);
            ov.y = f2h2(o2, o3);
            *(uint2*)(hout + (size_t)nodeA * 32 + 2 * w) = ov;
            if (hasB) {
                if (LAYER == 1) {
                    float4 bb = *(const float4*)(bias + 4 * w);
                    o0 = fmaxf(fmaf(dnB, aB0, bb.x), 0.f) * dnB;
                    o1 = fmaxf(fmaf(dnB, aB1, bb.y), 0.f) * dnB;
                    o2 = fmaxf(fmaf(dnB, aB2, bb.z), 0.f) * dnB;
                    o3 = fmaxf(fmaf(dnB, aB3, bb.w), 0.f) * dnB;
                } else {
                    o0 = dnB * aB0; o1 = dnB * aB1; o2 = dnB * aB2; o3 = dnB * aB3;
                }
                ov.x = f2h2(o0, o1);
                ov.y = f2h2(o2, o3);
                *(uint2*)(hout + (size_t)(nodeA + 1) * 32 + 2 * w) = ov;
            }
        }
        if (!more) break;
        nodeA = nxt;
        ntA = ntA_n;
        hasB = hasB_n;
        ntB = ntB_n;
    }
}

// out[n][96] = a2[n][64] @ W2[64][96] + b2.  fp16 tile (+1 pad) in LDS,
// 4 outputs/thread.
__global__ __launch_bounds__(256) void gemm2(const unsigned* __restrict__ a2h,
                                             const float* __restrict__ W2,
                                             const float* __restrict__ b2,
                                             float* __restrict__ out, int n) {
    __shared__ unsigned w2[32 * OUT_F];     // [k2][j], 12 KiB
    __shared__ float bs[OUT_F];
    __shared__ unsigned tile[256 * 33];     // +1 word pad per row
    for (int t = threadIdx.x; t < 32 * OUT_F; t += 256) {
        int k2 = t / OUT_F, j = t - k2 * OUT_F;
        w2[t] = f2h2(W2[(2 * k2) * OUT_F + j], W2[(2 * k2 + 1) * OUT_F + j]);
    }
    for (int t = threadIdx.x; t < OUT_F; t += 256) bs[t] = b2[t];
    const int base = blockIdx.x * 256;
    const int rows = min(256, n - base);
    const uint4* srcv = (const uint4*)(a2h + (size_t)base * 32);
    const int nvec = rows * 8;
    for (int t = threadIdx.x; t < nvec; t += 256) {
        uint4 v = srcv[t];
        int r = t >> 3, w0 = (t & 7) * 4;
        unsigned* d = &tile[r * 33 + w0];
        d[0] = v.x; d[1] = v.y; d[2] = v.z; d[3] = v.w;
    }
    __syncthreads();
    const int total = rows * 24;
    for (int idx = threadIdx.x; idx < total; idx += 256) {
        int r = idx / 24, jq = idx - r * 24, j = jq * 4;
        float4 bb = *(const float4*)&bs[j];
        float acc0 = bb.x, acc1 = bb.y, acc2 = bb.z, acc3 = bb.w;
        const unsigned* tr = &tile[r * 33];
#pragma unroll
        for (int k2 = 0; k2 < 32; ++k2) {
            unsigned tv = tr[k2];
            uint4 wv = *(const uint4*)&w2[k2 * OUT_F + j];
            acc0 = fdot2u(tv, wv.x, acc0);
            acc1 = fdot2u(tv, wv.y, acc1);
            acc2 = fdot2u(tv, wv.z, acc2);
            acc3 = fdot2u(tv, wv.w, acc3);
        }
        *(float4*)(out + (size_t)(base + r) * OUT_F + j) =
            make_float4(acc0, acc1, acc2, acc3);
    }
}

extern "C" void kernel_launch(void* const* d_in, const int* in_sizes, int n_in,
                              void* d_out, int out_size, void* d_ws, size_t ws_size,
                              hipStream_t stream) {
    const float* x  = (const float*)d_in[0];
    const int*   ei = (const int*)d_in[1];
    const float* W1 = (const float*)d_in[2];
    const float* b1 = (const float*)d_in[3];
    const float* W2 = (const float*)d_in[4];
    const float* b2 = (const float*)d_in[5];
    float* out = (float*)d_out;

    const int n = in_sizes[0] / IN_F;          // 100000
    const int E = in_sizes[1] / 2;             // 1600000
    const int* src = ei;
    const int* dst = ei + E;
    const int nbuck  = (n + 255) >> 8;         // 391
    const int nchunk = (E + CHUNK - 1) / CHUNK;// 391
    const int M = nbuck * nchunk;              // 152881
    const int NBS = (M + 1023) / 1024;
    const int ntile = (n + 255) / 256;         // 391

    char* ws = (char*)d_ws;
    size_t off = 0;
    auto alloc = [&](size_t bytes) { void* p = ws + off; off = (off + bytes + 255) & ~(size_t)255; return p; };
    int*      hist    = (int*)alloc((size_t)M * 4);
    int*      offs    = (int*)alloc((size_t)M * 4);
    int*      bsum    = (int*)alloc(256 * 4);
    int*      boffs   = (int*)alloc(256 * 4);
    unsigned* part    = (unsigned*)alloc((size_t)E * 4);
    int*      csr_src = (int*)alloc(((size_t)E + (size_t)nbuck * 4096 + 64) * 4);
    int4*     nodetab = (int4*)alloc((size_t)n * 16);
    float*    dinv    = (float*)alloc((size_t)n * 4);
    unsigned* hs      = (unsigned*)alloc((size_t)(n + 1) * 32 * 4);
    unsigned* hs2     = (unsigned*)alloc((size_t)(n + 1) * 32 * 4);
    unsigned* a2h     = (unsigned*)alloc((size_t)n * 32 * 4);

    // CSR build: histogram -> scan -> partition -> per-bucket padded finalize
    init_sentinel<<<1, 64, 0, stream>>>(hs, hs2, n);
    hist_chunks <<<nchunk, 256, 0, stream>>>(dst, hist, E, nbuck, nchunk);
    scan_blocks <<<NBS, 256, 0, stream>>>(hist, offs, bsum, M);
    scan_bsums  <<<1, 256, 0, stream>>>(bsum, boffs, NBS);
    partition   <<<nchunk, 256, 0, stream>>>(src, dst, offs, boffs, part, E, nbuck, nchunk);
    build_bucket<<<nbuck, 256, 0, stream>>>(part, offs, boffs, csr_src, nodetab, dinv,
                                            n, E, nbuck, nchunk);

    // network
    gemm1      <<<2048, 256, 0, stream>>>(x, W1, dinv, hs, n);
    csr_agg<1> <<<AGG_BLOCKS, 256, 0, stream>>>(nodetab, csr_src, hs, b1, hs2, n);
    csr_agg<2> <<<AGG_BLOCKS, 256, 0, stream>>>(nodetab, csr_src, hs2, NULL, a2h, n);
    gemm2      <<<ntile, 256, 0, stream>>>(a2h, W2, b2, out, n);
}

// Round 14
// 174.299 us; speedup vs baseline: 1.3025x; 1.3025x over previous
//
#include <hip/hip_runtime.h>
#include <hip/hip_fp16.h>

// ConformalGCN: 2-layer GCN, N=100000, E=1600000 (+self loops).
// R13: revert R12's readlane gemm1 (compiler rematerialized wreg, 95us).
//      gemm1 now uses MATRIX CORES: mfma_f32_16x16x32_f16, 16-row tiles
//      (n/16=6250 exact), B=W1 frags in registers, A=X rows fp16-converted.
//      Std CDNA frag maps: A row=lane&15,k=(lane>>4)*8+j; D col=lane&15,
//      row=(lane>>4)*4+reg (m89-verified). Rest = R10 best-known (186us).

#define IN_F  128
#define HID_F 64
#define OUT_F 96
#define CHUNK 4096
#define MAXB  12288         // stage capacity (padded bucket size), 48 KiB
#define AGG_BLOCKS 4096
#define ONE_LO 0x00003C00u  // fp16 (1.0, 0.0)
#define ONE_HI 0x3C000000u  // fp16 (0.0, 1.0)

typedef _Float16 f16x2 __attribute__((ext_vector_type(2)));
typedef _Float16 half8 __attribute__((ext_vector_type(8)));
typedef float floatx4 __attribute__((ext_vector_type(4)));

__device__ __forceinline__ float2 unpack2(unsigned u) {
    __half2 h = *reinterpret_cast<__half2*>(&u);
    return __half22float2(h);
}
__device__ __forceinline__ unsigned f2h2(float lo, float hi) {
    __half2 h = __floats2half2_rn(lo, hi);
    return *reinterpret_cast<unsigned*>(&h);
}

#if defined(__has_builtin)
#if __has_builtin(__builtin_amdgcn_fdot2)
#define HAS_FDOT2 1
#endif
#if __has_builtin(__builtin_amdgcn_mfma_f32_16x16x32_f16)
#define HAS_MFMA 1
#endif
#endif
#ifndef HAS_FDOT2
#define HAS_FDOT2 0
#endif
#ifndef HAS_MFMA
#define HAS_MFMA 0
#endif

__device__ __forceinline__ float fdot2u(unsigned a, unsigned b, float c) {
#if HAS_FDOT2
    return __builtin_amdgcn_fdot2(__builtin_bit_cast(f16x2, a),
                                  __builtin_bit_cast(f16x2, b), c, false);
#else
    float2 fa = unpack2(a), fb = unpack2(b);
    return fmaf(fa.y, fb.y, fmaf(fa.x, fb.x, c));
#endif
}

// zero the sentinel feature rows hs[n], hs2[n]
__global__ __launch_bounds__(64) void init_sentinel(unsigned* __restrict__ hs,
                                                    unsigned* __restrict__ hs2, int n) {
    int t = threadIdx.x;
    if (t < 32) {
        hs[(size_t)n * 32 + t] = 0u;
        hs2[(size_t)n * 32 + t] = 0u;
    }
}

// ---- pass 1a: per-chunk bucket histograms (bucket-major layout) ----
__global__ __launch_bounds__(256) void hist_chunks(const int* __restrict__ dst,
                                                   int* __restrict__ hist,
                                                   int E, int nbuck, int nchunk) {
    __shared__ int cnt[512];
    for (int i = threadIdx.x; i < nbuck; i += 256) cnt[i] = 0;
    __syncthreads();
    const int base = blockIdx.x * CHUNK;
    const int lim = min(base + CHUNK, E);
    for (int e = base + threadIdx.x; e < lim; e += 256)
        atomicAdd(&cnt[dst[e] >> 8], 1);
    __syncthreads();
    for (int b = threadIdx.x; b < nbuck; b += 256)
        hist[b * nchunk + blockIdx.x] = cnt[b];
}

// ---- hierarchical exclusive prefix sum (1024 elems/block) ----
__global__ __launch_bounds__(256) void scan_blocks(const int* __restrict__ in,
                                                   int* __restrict__ pre,
                                                   int* __restrict__ bsum, int m) {
    __shared__ int lds[256];
    const int t = threadIdx.x;
    const int base = blockIdx.x * 1024 + t * 4;
    int v0 = (base + 0 < m) ? in[base + 0] : 0;
    int v1 = (base + 1 < m) ? in[base + 1] : 0;
    int v2 = (base + 2 < m) ? in[base + 2] : 0;
    int v3 = (base + 3 < m) ? in[base + 3] : 0;
    int s = v0 + v1 + v2 + v3;
    lds[t] = s;
    __syncthreads();
    for (int off = 1; off < 256; off <<= 1) {
        int add = (t >= off) ? lds[t - off] : 0;
        __syncthreads();
        lds[t] += add;
        __syncthreads();
    }
    int e = lds[t] - s;
    if (base + 0 < m) pre[base + 0] = e;
    e += v0;
    if (base + 1 < m) pre[base + 1] = e;
    e += v1;
    if (base + 2 < m) pre[base + 2] = e;
    e += v2;
    if (base + 3 < m) pre[base + 3] = e;
    if (t == 255) bsum[blockIdx.x] = lds[255];
}

__global__ __launch_bounds__(256) void scan_bsums(const int* __restrict__ bsum,
                                                  int* __restrict__ boffs, int nb) {
    __shared__ int lds[256];
    const int t = threadIdx.x;
    int v = (t < nb) ? bsum[t] : 0;
    lds[t] = v;
    __syncthreads();
    for (int off = 1; off < 256; off <<= 1) {
        int add = (t >= off) ? lds[t - off] : 0;
        __syncthreads();
        lds[t] += add;
        __syncthreads();
    }
    boffs[t] = lds[t] - v;
}

// ---- pass 1b: partition edges into bucket-grouped runs, 4B records ----
__global__ __launch_bounds__(256) void partition(const int* __restrict__ src,
                                                 const int* __restrict__ dst,
                                                 const int* __restrict__ offs,
                                                 const int* __restrict__ boffs,
                                                 unsigned* __restrict__ part,
                                                 int E, int nbuck, int nchunk) {
    __shared__ int off[512];
    for (int b = threadIdx.x; b < nbuck; b += 256) {
        int idx = b * nchunk + blockIdx.x;
        off[b] = offs[idx] + boffs[idx >> 10];
    }
    __syncthreads();
    const int base = blockIdx.x * CHUNK;
    const int lim = min(base + CHUNK, E);
    for (int e = base + threadIdx.x; e < lim; e += 256) {
        int d = dst[e], s = src[e];
        int pos = atomicAdd(&off[d >> 8], 1);
        part[pos] = ((unsigned)s << 8) | (unsigned)(d & 255);
    }
}

// ---- pass 2: per-bucket padded CSR finalize ----
__global__ __launch_bounds__(256) void build_bucket(const unsigned* __restrict__ part,
                                                    const int* __restrict__ offs,
                                                    const int* __restrict__ boffs,
                                                    int* __restrict__ csr_src,
                                                    int4* __restrict__ nodetab,
                                                    float* __restrict__ dinv,
                                                    int n, int E, int nbuck, int nchunk) {
    __shared__ int cnt[256], sc[256], off[256];
    __shared__ int stage[MAXB];
    const int b = blockIdx.x;
    const int t = threadIdx.x;
    const int i0 = b * nchunk;
    const int bstart = offs[i0] + boffs[i0 >> 10];
    int bend = E;
    if (b + 1 < nbuck) {
        const int i1 = (b + 1) * nchunk;
        bend = offs[i1] + boffs[i1 >> 10];
    }
    const int bstart_pad = bstart + b * 4096;
    const int nodebase = b << 8;
    const int nnodes = min(256, n - nodebase);

    cnt[t] = 0;
    __syncthreads();
    for (int i = bstart + t; i < bend; i += 256)
        atomicAdd(&cnt[part[i] & 255u], 1);
    __syncthreads();
    const int deg = cnt[t];
    const int pdeg = (deg + 15) & ~15;
    sc[t] = pdeg;
    __syncthreads();
    for (int o = 1; o < 256; o <<= 1) {
        int add = (t >= o) ? sc[t - o] : 0;
        __syncthreads();
        sc[t] += add;
        __syncthreads();
    }
    const int pexcl = sc[t] - pdeg;
    const int psize = sc[255];
    if (t < nnodes) {
        float dv = rsqrtf((float)(deg + 1));   // +1 self loop
        nodetab[nodebase + t] = make_int4(bstart_pad + pexcl,
                                          bstart_pad + pexcl + pdeg,
                                          __float_as_int(dv), 0);
        dinv[nodebase + t] = dv;
    }
    off[t] = pexcl;
    __syncthreads();

    if (psize <= MAXB) {
        for (int i = t; i < psize; i += 256) stage[i] = n;   // sentinel fill
        __syncthreads();
        for (int i = bstart + t; i < bend; i += 256) {
            unsigned r = part[i];
            int pos = atomicAdd(&off[r & 255u], 1);
            stage[pos] = (int)(r >> 8);
        }
        __syncthreads();
        for (int i = t; i < psize; i += 256)
            csr_src[bstart_pad + i] = stage[i];
    } else {   // safety fallback
        for (int i = t; i < psize; i += 256) csr_src[bstart_pad + i] = n;
        __syncthreads();
        for (int i = bstart + t; i < bend; i += 256) {
            unsigned r = part[i];
            int pos = atomicAdd(&off[r & 255u], 1);
            csr_src[bstart_pad + pos] = (int)(r >> 8);
        }
    }
}

// hs[row] = fp16x2( dinv[row] * (x[row] @ W1) ).  MFMA version: one wave per
// 16-row tile; A = X rows (fp16 cvt), B = W1 frags preloaded in registers.
// A: row=lane&15, k=(lane>>4)*8+j.  D: col=lane&15, row=(lane>>4)*4+reg.
__global__ __launch_bounds__(256) void gemm1(const float* __restrict__ x,
                                             const float* __restrict__ W1,
                                             const float* __restrict__ dinv,
                                             unsigned* __restrict__ hs, int n) {
#if HAS_MFMA
    const int lane = threadIdx.x & 63;
    const int wave = threadIdx.x >> 6;
    const int q4 = lane >> 4;          // 0..3
    const int l16 = lane & 15;
    // B fragments: bfrag[ks][cb][j] = W1[ks*32 + q4*8 + j][cb*16 + l16]
    half8 bfrag[4][4];
#pragma unroll
    for (int ks = 0; ks < 4; ++ks)
#pragma unroll
        for (int cb = 0; cb < 4; ++cb)
#pragma unroll
            for (int j = 0; j < 8; ++j)
                bfrag[ks][cb][j] =
                    (_Float16)W1[(ks * 32 + q4 * 8 + j) * HID_F + cb * 16 + l16];

    const int ntile = (n + 15) >> 4;   // n=100000 -> 6250 exact
    for (int t = blockIdx.x * 4 + wave; t < ntile; t += gridDim.x * 4) {
        const int r0 = t << 4;
        const int arow = min(r0 + l16, n - 1);
        const float* xr = x + (size_t)arow * IN_F + q4 * 8;
        half8 afrag[4];
#pragma unroll
        for (int ks = 0; ks < 4; ++ks) {
            float4 v0 = *(const float4*)(xr + ks * 32);
            float4 v1 = *(const float4*)(xr + ks * 32 + 4);
            half8 a;
            a[0] = (_Float16)v0.x; a[1] = (_Float16)v0.y;
            a[2] = (_Float16)v0.z; a[3] = (_Float16)v0.w;
            a[4] = (_Float16)v1.x; a[5] = (_Float16)v1.y;
            a[6] = (_Float16)v1.z; a[7] = (_Float16)v1.w;
            afrag[ks] = a;
        }
        floatx4 acc[4] = {{0.f,0.f,0.f,0.f},{0.f,0.f,0.f,0.f},
                          {0.f,0.f,0.f,0.f},{0.f,0.f,0.f,0.f}};
#pragma unroll
        for (int ks = 0; ks < 4; ++ks) {
#pragma unroll
            for (int cb = 0; cb < 4; ++cb)
                acc[cb] = __builtin_amdgcn_mfma_f32_16x16x32_f16(
                    afrag[ks], bfrag[ks][cb], acc[cb], 0, 0, 0);
        }
        // lane holds D[q4*4+reg][cb*16+l16]; rows rbase..rbase+3
        const int rbase = r0 + q4 * 4;
        float4 dvv = *(const float4*)(dinv + rbase);
        float dvr[4] = {dvv.x, dvv.y, dvv.z, dvv.w};
#pragma unroll
        for (int cb = 0; cb < 4; ++cb) {
#pragma unroll
            for (int reg = 0; reg < 4; ++reg) {
                float v = acc[cb][reg] * dvr[reg];
                float o = __shfl_xor(v, 1);          // partner column
                if (!(l16 & 1)) {
                    int r = rbase + reg;
                    if (r < n)
                        hs[(size_t)r * 32 + cb * 8 + (l16 >> 1)] = f2h2(v, o);
                }
            }
        }
    }
#else
    // fallback: R10 LDS-staged dot2 path
    __shared__ unsigned w2[64 * HID_F];
    __shared__ uint4 xs4[4][64];
    for (int t = threadIdx.x; t < 64 * HID_F; t += 256) {
        int k2 = t >> 6, col = t & 63;
        w2[t] = f2h2(W1[(2 * k2) * HID_F + col], W1[(2 * k2 + 1) * HID_F + col]);
    }
    __syncthreads();
    const int wave = threadIdx.x >> 6, lane = threadIdx.x & 63;
    const int nquad = (n + 3) >> 2;
    for (int q = blockIdx.x * 4 + wave; q < nquad; q += gridDim.x * 4) {
        const int r0 = q * 4;
        const bool h1 = r0 + 1 < n, h2 = r0 + 2 < n, h3 = r0 + 3 < n;
        const float* xp = x + (size_t)r0 * IN_F + lane * 2;
        float2 v0 = *(const float2*)(xp);
        float2 v1 = h1 ? *(const float2*)(xp + IN_F)     : make_float2(0.f, 0.f);
        float2 v2 = h2 ? *(const float2*)(xp + 2 * IN_F) : make_float2(0.f, 0.f);
        float2 v3 = h3 ? *(const float2*)(xp + 3 * IN_F) : make_float2(0.f, 0.f);
        uint4 pk;
        pk.x = f2h2(v0.x, v0.y); pk.y = f2h2(v1.x, v1.y);
        pk.z = f2h2(v2.x, v2.y); pk.w = f2h2(v3.x, v3.y);
        xs4[wave][lane] = pk;
        float a0 = 0.f, a1 = 0.f, a2 = 0.f, a3 = 0.f;
#pragma unroll 8
        for (int k2 = 0; k2 < 64; ++k2) {
            uint4 xv = xs4[wave][k2];
            unsigned wv = w2[k2 * 64 + lane];
            a0 = fdot2u(xv.x, wv, a0);
            a1 = fdot2u(xv.y, wv, a1);
            a2 = fdot2u(xv.z, wv, a2);
            a3 = fdot2u(xv.w, wv, a3);
        }
        a0 *= dinv[r0];
        a1 *= h1 ? dinv[r0 + 1] : 0.f;
        a2 *= h2 ? dinv[r0 + 2] : 0.f;
        a3 *= h3 ? dinv[r0 + 3] : 0.f;
        float o0 = __shfl_xor(a0, 1), o1 = __shfl_xor(a1, 1);
        float o2 = __shfl_xor(a2, 1), o3 = __shfl_xor(a3, 1);
        if (!(lane & 1)) {
            int wd = lane >> 1;
            hs[(size_t)r0 * 32 + wd] = f2h2(a0, o0);
            if (h1) hs[(size_t)(r0 + 1) * 32 + wd] = f2h2(a1, o1);
            if (h2) hs[(size_t)(r0 + 2) * 32 + wd] = f2h2(a2, o2);
            if (h3) hs[(size_t)(r0 + 3) * 32 + wd] = f2h2(a3, o3);
        }
    }
#endif
}

// Grid-stride; each wave owns TWO consecutive nodes with interleaved
// branchless gather chains.  Rows padded to %16.  fdot2 lane-extract accum.
#define ACC2(u, slo, shi) { slo = fdot2u(u, ONE_LO, slo); shi = fdot2u(u, ONE_HI, shi); }
template <int LAYER>
__global__ __launch_bounds__(256) void csr_agg(const int4* __restrict__ nodetab,
                                               const int* __restrict__ csr_src,
                                               const unsigned* __restrict__ hs,
                                               const float* __restrict__ bias,
                                               unsigned* __restrict__ hout, int n) {
    const int lane = threadIdx.x & 63;
    const int g = lane >> 4;          // edge slot 0..3
    const int w = lane & 15;          // feats 4w..4w+3
    const unsigned* __restrict__ hw = hs + 2 * w;
    const int STR = gridDim.x * 8;
    const int SENT = n;

    int nodeA = (blockIdx.x * 4 + (threadIdx.x >> 6)) * 2;
    if (nodeA >= n) return;
    int4 ntA = nodetab[nodeA];
    bool hasB = nodeA + 1 < n;
    int4 ntB = hasB ? nodetab[nodeA + 1] : make_int4(0, 0, 0, 0);

    for (;;) {
        const int nxt = nodeA + STR;
        const bool more = nxt < n;
        int4 ntA_n, ntB_n;
        bool hasB_n = false;
        if (more) {
            ntA_n = nodetab[nxt];
            hasB_n = nxt + 1 < n;
            if (hasB_n) ntB_n = nodetab[nxt + 1];
        }

        int pA = ntA.x;
        const int endA = ntA.y;
        const float dnA = __int_as_float(ntA.z);
        int pB = hasB ? ntB.x : 0;
        const int endB = hasB ? ntB.y : 0;
        const float dnB = hasB ? __int_as_float(ntB.z) : 0.f;

        float aA0 = 0.f, aA1 = 0.f, aA2 = 0.f, aA3 = 0.f;
        float cA0 = 0.f, cA1 = 0.f, cA2 = 0.f, cA3 = 0.f;
        float aB0 = 0.f, aB1 = 0.f, aB2 = 0.f, aB3 = 0.f;
        float cB0 = 0.f, cB1 = 0.f, cB2 = 0.f, cB3 = 0.f;
        if (g == 0) {                                      // self loops, once
            uint2 suA = *(const uint2*)(hw + (size_t)nodeA * 32);
            ACC2(suA.x, aA0, aA1);
            ACC2(suA.y, aA2, aA3);
            if (hasB) {
                uint2 suB = *(const uint2*)(hw + (size_t)(nodeA + 1) * 32);
                ACC2(suB.x, aB0, aB1);
                ACC2(suB.y, aB2, aB3);
            }
        }
        while (pA < endA || pB < endB) {
            int4 ivA = (pA < endA) ? *(const int4*)&csr_src[pA + 4 * g]
                                   : make_int4(SENT, SENT, SENT, SENT);
            int4 ivB = (pB < endB) ? *(const int4*)&csr_src[pB + 4 * g]
                                   : make_int4(SENT, SENT, SENT, SENT);
            uint2 uA0 = *(const uint2*)(hw + (size_t)ivA.x * 32);
            uint2 uA1 = *(const uint2*)(hw + (size_t)ivA.y * 32);
            uint2 uA2 = *(const uint2*)(hw + (size_t)ivA.z * 32);
            uint2 uA3 = *(const uint2*)(hw + (size_t)ivA.w * 32);
            uint2 uB0 = *(const uint2*)(hw + (size_t)ivB.x * 32);
            uint2 uB1 = *(const uint2*)(hw + (size_t)ivB.y * 32);
            uint2 uB2 = *(const uint2*)(hw + (size_t)ivB.z * 32);
            uint2 uB3 = *(const uint2*)(hw + (size_t)ivB.w * 32);
            ACC2(uA0.x, aA0, aA1); ACC2(uA0.y, aA2, aA3);
            ACC2(uA1.x, cA0, cA1); ACC2(uA1.y, cA2, cA3);
            ACC2(uA2.x, aA0, aA1); ACC2(uA2.y, aA2, aA3);
            ACC2(uA3.x, cA0, cA1); ACC2(uA3.y, cA2, cA3);
            ACC2(uB0.x, aB0, aB1); ACC2(uB0.y, aB2, aB3);
            ACC2(uB1.x, cB0, cB1); ACC2(uB1.y, cB2, cB3);
            ACC2(uB2.x, aB0, aB1); ACC2(uB2.y, aB2, aB3);
            ACC2(uB3.x, cB0, cB1); ACC2(uB3.y, cB2, cB3);
            pA += 16; pB += 16;
        }
        aA0 += cA0; aA1 += cA1; aA2 += cA2; aA3 += cA3;
        aB0 += cB0; aB1 += cB1; aB2 += cB2; aB3 += cB3;
        aA0 += __shfl_xor(aA0, 16); aA0 += __shfl_xor(aA0, 32);
        aA1 += __shfl_xor(aA1, 16); aA1 += __shfl_xor(aA1, 32);
        aA2 += __shfl_xor(aA2, 16); aA2 += __shfl_xor(aA2, 32);
        aA3 += __shfl_xor(aA3, 16); aA3 += __shfl_xor(aA3, 32);
        aB0 += __shfl_xor(aB0, 16); aB0 += __shfl_xor(aB0, 32);
        aB1 += __shfl_xor(aB1, 16); aB1 += __shfl_xor(aB1, 32);
        aB2 += __shfl_xor(aB2, 16); aB2 += __shfl_xor(aB2, 32);
        aB3 += __shfl_xor(aB3, 16); aB3 += __shfl_xor(aB3, 32);

        if (g == 0) {
            float o0, o1, o2, o3;
            if (LAYER == 1) {
                float4 bb = *(const float4*)(bias + 4 * w);
                o0 = fmaxf(fmaf(dnA, aA0, bb.x), 0.f) * dnA;
                o1 = fmaxf(fmaf(dnA, aA1, bb.y), 0.f) * dnA;
                o2 = fmaxf(fmaf(dnA, aA2, bb.z), 0.f) * dnA;
                o3 = fmaxf(fmaf(dnA, aA3, bb.w), 0.f) * dnA;
            } else {
                o0 = dnA * aA0; o1 = dnA * aA1; o2 = dnA * aA2; o3 = dnA * aA3;
            }
            uint2 ov;
            ov.x = f2h2(o0, o1);
            ov.y = f2h2(o2, o3);
            *(uint2*)(hout + (size_t)nodeA * 32 + 2 * w) = ov;
            if (hasB) {
                if (LAYER == 1) {
                    float4 bb = *(const float4*)(bias + 4 * w);
                    o0 = fmaxf(fmaf(dnB, aB0, bb.x), 0.f) * dnB;
                    o1 = fmaxf(fmaf(dnB, aB1, bb.y), 0.f) * dnB;
                    o2 = fmaxf(fmaf(dnB, aB2, bb.z), 0.f) * dnB;
                    o3 = fmaxf(fmaf(dnB, aB3, bb.w), 0.f) * dnB;
                } else {
                    o0 = dnB * aB0; o1 = dnB * aB1; o2 = dnB * aB2; o3 = dnB * aB3;
                }
                ov.x = f2h2(o0, o1);
                ov.y = f2h2(o2, o3);
                *(uint2*)(hout + (size_t)(nodeA + 1) * 32 + 2 * w) = ov;
            }
        }
        if (!more) break;
        nodeA = nxt;
        ntA = ntA_n;
        hasB = hasB_n;
        ntB = ntB_n;
    }
}

// out[n][96] = a2[n][64] @ W2[64][96] + b2.  fp16 tile (+1 pad) in LDS,
// 4 outputs/thread.
__global__ __launch_bounds__(256) void gemm2(const unsigned* __restrict__ a2h,
                                             const float* __restrict__ W2,
                                             const float* __restrict__ b2,
                                             float* __restrict__ out, int n) {
    __shared__ unsigned w2[32 * OUT_F];     // [k2][j], 12 KiB
    __shared__ float bs[OUT_F];
    __shared__ unsigned tile[256 * 33];     // +1 word pad per row
    for (int t = threadIdx.x; t < 32 * OUT_F; t += 256) {
        int k2 = t / OUT_F, j = t - k2 * OUT_F;
        w2[t] = f2h2(W2[(2 * k2) * OUT_F + j], W2[(2 * k2 + 1) * OUT_F + j]);
    }
    for (int t = threadIdx.x; t < OUT_F; t += 256) bs[t] = b2[t];
    const int base = blockIdx.x * 256;
    const int rows = min(256, n - base);
    const uint4* srcv = (const uint4*)(a2h + (size_t)base * 32);
    const int nvec = rows * 8;
    for (int t = threadIdx.x; t < nvec; t += 256) {
        uint4 v = srcv[t];
        int r = t >> 3, w0 = (t & 7) * 4;
        unsigned* d = &tile[r * 33 + w0];
        d[0] = v.x; d[1] = v.y; d[2] = v.z; d[3] = v.w;
    }
    __syncthreads();
    const int total = rows * 24;
    for (int idx = threadIdx.x; idx < total; idx += 256) {
        int r = idx / 24, jq = idx - r * 24, j = jq * 4;
        float4 bb = *(const float4*)&bs[j];
        float acc0 = bb.x, acc1 = bb.y, acc2 = bb.z, acc3 = bb.w;
        const unsigned* tr = &tile[r * 33];
#pragma unroll
        for (int k2 = 0; k2 < 32; ++k2) {
            unsigned tv = tr[k2];
            uint4 wv = *(const uint4*)&w2[k2 * OUT_F + j];
            acc0 = fdot2u(tv, wv.x, acc0);
            acc1 = fdot2u(tv, wv.y, acc1);
            acc2 = fdot2u(tv, wv.z, acc2);
            acc3 = fdot2u(tv, wv.w, acc3);
        }
        *(float4*)(out + (size_t)(base + r) * OUT_F + j) =
            make_float4(acc0, acc1, acc2, acc3);
    }
}

extern "C" void kernel_launch(void* const* d_in, const int* in_sizes, int n_in,
                              void* d_out, int out_size, void* d_ws, size_t ws_size,
                              hipStream_t stream) {
    const float* x  = (const float*)d_in[0];
    const int*   ei = (const int*)d_in[1];
    const float* W1 = (const float*)d_in[2];
    const float* b1 = (const float*)d_in[3];
    const float* W2 = (const float*)d_in[4];
    const float* b2 = (const float*)d_in[5];
    float* out = (float*)d_out;

    const int n = in_sizes[0] / IN_F;          // 100000
    const int E = in_sizes[1] / 2;             // 1600000
    const int* src = ei;
    const int* dst = ei + E;
    const int nbuck  = (n + 255) >> 8;         // 391
    const int nchunk = (E + CHUNK - 1) / CHUNK;// 391
    const int M = nbuck * nchunk;              // 152881
    const int NBS = (M + 1023) / 1024;
    const int ntile = (n + 255) / 256;         // 391
    const int g1tiles = (n + 15) / 16;         // 6250
    const int g1blocks = (g1tiles + 7) / 8;    // 2 tiles/wave -> 782

    char* ws = (char*)d_ws;
    size_t off = 0;
    auto alloc = [&](size_t bytes) { void* p = ws + off; off = (off + bytes + 255) & ~(size_t)255; return p; };
    int*      hist    = (int*)alloc((size_t)M * 4);
    int*      offs    = (int*)alloc((size_t)M * 4);
    int*      bsum    = (int*)alloc(256 * 4);
    int*      boffs   = (int*)alloc(256 * 4);
    unsigned* part    = (unsigned*)alloc((size_t)E * 4);
    int*      csr_src = (int*)alloc(((size_t)E + (size_t)nbuck * 4096 + 64) * 4);
    int4*     nodetab = (int4*)alloc((size_t)n * 16);
    float*    dinv    = (float*)alloc((size_t)n * 4);
    unsigned* hs      = (unsigned*)alloc((size_t)(n + 1) * 32 * 4);
    unsigned* hs2     = (unsigned*)alloc((size_t)(n + 1) * 32 * 4);
    unsigned* a2h     = (unsigned*)alloc((size_t)n * 32 * 4);

    // CSR build: histogram -> scan -> partition -> per-bucket padded finalize
    init_sentinel<<<1, 64, 0, stream>>>(hs, hs2, n);
    hist_chunks <<<nchunk, 256, 0, stream>>>(dst, hist, E, nbuck, nchunk);
    scan_blocks <<<NBS, 256, 0, stream>>>(hist, offs, bsum, M);
    scan_bsums  <<<1, 256, 0, stream>>>(bsum, boffs, NBS);
    partition   <<<nchunk, 256, 0, stream>>>(src, dst, offs, boffs, part, E, nbuck, nchunk);
    build_bucket<<<nbuck, 256, 0, stream>>>(part, offs, boffs, csr_src, nodetab, dinv,
                                            n, E, nbuck, nchunk);

    // network
    gemm1      <<<g1blocks, 256, 0, stream>>>(x, W1, dinv, hs, n);
    csr_agg<1> <<<AGG_BLOCKS, 256, 0, stream>>>(nodetab, csr_src, hs, b1, hs2, n);
    csr_agg<2> <<<AGG_BLOCKS, 256, 0, stream>>>(nodetab, csr_src, hs2, NULL, a2h, n);
    gemm2      <<<ntile, 256, 0, stream>>>(a2h, W2, b2, out, n);
}

// Round 15
// 158.866 us; speedup vs baseline: 1.4290x; 1.0971x over previous
//
#include <hip/hip_runtime.h>
#include <hip/hip_fp16.h>

// ConformalGCN: 2-layer GCN, N=100000, E=1600000 (+self loops).
// R14: (1) csr_agg 4-node interleave (2x MLP per wave; FETCH is at the
//      compulsory-miss floor, gather is outstanding-limited); (2) gemm2 on
//      matrix cores reusing R13's HW-verified fragment mapping (a2h rows are
//      already A-fragment-ordered fp16). gemm1 MFMA + radix CSR = R13.

#define IN_F  128
#define HID_F 64
#define OUT_F 96
#define CHUNK 4096
#define MAXB  12288         // stage capacity (padded bucket size), 48 KiB
#define AGG_BLOCKS 4096
#define ONE_LO 0x00003C00u  // fp16 (1.0, 0.0)
#define ONE_HI 0x3C000000u  // fp16 (0.0, 1.0)

typedef _Float16 f16x2 __attribute__((ext_vector_type(2)));
typedef _Float16 half8 __attribute__((ext_vector_type(8)));
typedef float floatx4 __attribute__((ext_vector_type(4)));

__device__ __forceinline__ float2 unpack2(unsigned u) {
    __half2 h = *reinterpret_cast<__half2*>(&u);
    return __half22float2(h);
}
__device__ __forceinline__ unsigned f2h2(float lo, float hi) {
    __half2 h = __floats2half2_rn(lo, hi);
    return *reinterpret_cast<unsigned*>(&h);
}

#if defined(__has_builtin)
#if __has_builtin(__builtin_amdgcn_fdot2)
#define HAS_FDOT2 1
#endif
#if __has_builtin(__builtin_amdgcn_mfma_f32_16x16x32_f16)
#define HAS_MFMA 1
#endif
#endif
#ifndef HAS_FDOT2
#define HAS_FDOT2 0
#endif
#ifndef HAS_MFMA
#define HAS_MFMA 0
#endif

__device__ __forceinline__ float fdot2u(unsigned a, unsigned b, float c) {
#if HAS_FDOT2
    return __builtin_amdgcn_fdot2(__builtin_bit_cast(f16x2, a),
                                  __builtin_bit_cast(f16x2, b), c, false);
#else
    float2 fa = unpack2(a), fb = unpack2(b);
    return fmaf(fa.y, fb.y, fmaf(fa.x, fb.x, c));
#endif
}

// zero the sentinel feature rows hs[n], hs2[n]
__global__ __launch_bounds__(64) void init_sentinel(unsigned* __restrict__ hs,
                                                    unsigned* __restrict__ hs2, int n) {
    int t = threadIdx.x;
    if (t < 32) {
        hs[(size_t)n * 32 + t] = 0u;
        hs2[(size_t)n * 32 + t] = 0u;
    }
}

// ---- pass 1a: per-chunk bucket histograms (bucket-major layout) ----
__global__ __launch_bounds__(256) void hist_chunks(const int* __restrict__ dst,
                                                   int* __restrict__ hist,
                                                   int E, int nbuck, int nchunk) {
    __shared__ int cnt[512];
    for (int i = threadIdx.x; i < nbuck; i += 256) cnt[i] = 0;
    __syncthreads();
    const int base = blockIdx.x * CHUNK;
    const int lim = min(base + CHUNK, E);
    for (int e = base + threadIdx.x; e < lim; e += 256)
        atomicAdd(&cnt[dst[e] >> 8], 1);
    __syncthreads();
    for (int b = threadIdx.x; b < nbuck; b += 256)
        hist[b * nchunk + blockIdx.x] = cnt[b];
}

// ---- hierarchical exclusive prefix sum (1024 elems/block) ----
__global__ __launch_bounds__(256) void scan_blocks(const int* __restrict__ in,
                                                   int* __restrict__ pre,
                                                   int* __restrict__ bsum, int m) {
    __shared__ int lds[256];
    const int t = threadIdx.x;
    const int base = blockIdx.x * 1024 + t * 4;
    int v0 = (base + 0 < m) ? in[base + 0] : 0;
    int v1 = (base + 1 < m) ? in[base + 1] : 0;
    int v2 = (base + 2 < m) ? in[base + 2] : 0;
    int v3 = (base + 3 < m) ? in[base + 3] : 0;
    int s = v0 + v1 + v2 + v3;
    lds[t] = s;
    __syncthreads();
    for (int off = 1; off < 256; off <<= 1) {
        int add = (t >= off) ? lds[t - off] : 0;
        __syncthreads();
        lds[t] += add;
        __syncthreads();
    }
    int e = lds[t] - s;
    if (base + 0 < m) pre[base + 0] = e;
    e += v0;
    if (base + 1 < m) pre[base + 1] = e;
    e += v1;
    if (base + 2 < m) pre[base + 2] = e;
    e += v2;
    if (base + 3 < m) pre[base + 3] = e;
    if (t == 255) bsum[blockIdx.x] = lds[255];
}

__global__ __launch_bounds__(256) void scan_bsums(const int* __restrict__ bsum,
                                                  int* __restrict__ boffs, int nb) {
    __shared__ int lds[256];
    const int t = threadIdx.x;
    int v = (t < nb) ? bsum[t] : 0;
    lds[t] = v;
    __syncthreads();
    for (int off = 1; off < 256; off <<= 1) {
        int add = (t >= off) ? lds[t - off] : 0;
        __syncthreads();
        lds[t] += add;
        __syncthreads();
    }
    boffs[t] = lds[t] - v;
}

// ---- pass 1b: partition edges into bucket-grouped runs, 4B records ----
__global__ __launch_bounds__(256) void partition(const int* __restrict__ src,
                                                 const int* __restrict__ dst,
                                                 const int* __restrict__ offs,
                                                 const int* __restrict__ boffs,
                                                 unsigned* __restrict__ part,
                                                 int E, int nbuck, int nchunk) {
    __shared__ int off[512];
    for (int b = threadIdx.x; b < nbuck; b += 256) {
        int idx = b * nchunk + blockIdx.x;
        off[b] = offs[idx] + boffs[idx >> 10];
    }
    __syncthreads();
    const int base = blockIdx.x * CHUNK;
    const int lim = min(base + CHUNK, E);
    for (int e = base + threadIdx.x; e < lim; e += 256) {
        int d = dst[e], s = src[e];
        int pos = atomicAdd(&off[d >> 8], 1);
        part[pos] = ((unsigned)s << 8) | (unsigned)(d & 255);
    }
}

// ---- pass 2: per-bucket padded CSR finalize ----
__global__ __launch_bounds__(256) void build_bucket(const unsigned* __restrict__ part,
                                                    const int* __restrict__ offs,
                                                    const int* __restrict__ boffs,
                                                    int* __restrict__ csr_src,
                                                    int4* __restrict__ nodetab,
                                                    float* __restrict__ dinv,
                                                    int n, int E, int nbuck, int nchunk) {
    __shared__ int cnt[256], sc[256], off[256];
    __shared__ int stage[MAXB];
    const int b = blockIdx.x;
    const int t = threadIdx.x;
    const int i0 = b * nchunk;
    const int bstart = offs[i0] + boffs[i0 >> 10];
    int bend = E;
    if (b + 1 < nbuck) {
        const int i1 = (b + 1) * nchunk;
        bend = offs[i1] + boffs[i1 >> 10];
    }
    const int bstart_pad = bstart + b * 4096;
    const int nodebase = b << 8;
    const int nnodes = min(256, n - nodebase);

    cnt[t] = 0;
    __syncthreads();
    for (int i = bstart + t; i < bend; i += 256)
        atomicAdd(&cnt[part[i] & 255u], 1);
    __syncthreads();
    const int deg = cnt[t];
    const int pdeg = (deg + 15) & ~15;
    sc[t] = pdeg;
    __syncthreads();
    for (int o = 1; o < 256; o <<= 1) {
        int add = (t >= o) ? sc[t - o] : 0;
        __syncthreads();
        sc[t] += add;
        __syncthreads();
    }
    const int pexcl = sc[t] - pdeg;
    const int psize = sc[255];
    if (t < nnodes) {
        float dv = rsqrtf((float)(deg + 1));   // +1 self loop
        nodetab[nodebase + t] = make_int4(bstart_pad + pexcl,
                                          bstart_pad + pexcl + pdeg,
                                          __float_as_int(dv), 0);
        dinv[nodebase + t] = dv;
    }
    off[t] = pexcl;
    __syncthreads();

    if (psize <= MAXB) {
        for (int i = t; i < psize; i += 256) stage[i] = n;   // sentinel fill
        __syncthreads();
        for (int i = bstart + t; i < bend; i += 256) {
            unsigned r = part[i];
            int pos = atomicAdd(&off[r & 255u], 1);
            stage[pos] = (int)(r >> 8);
        }
        __syncthreads();
        for (int i = t; i < psize; i += 256)
            csr_src[bstart_pad + i] = stage[i];
    } else {   // safety fallback
        for (int i = t; i < psize; i += 256) csr_src[bstart_pad + i] = n;
        __syncthreads();
        for (int i = bstart + t; i < bend; i += 256) {
            unsigned r = part[i];
            int pos = atomicAdd(&off[r & 255u], 1);
            csr_src[bstart_pad + pos] = (int)(r >> 8);
        }
    }
}

// hs[row] = fp16x2( dinv[row] * (x[row] @ W1) ).  MFMA (R13, HW-verified).
__global__ __launch_bounds__(256) void gemm1(const float* __restrict__ x,
                                             const float* __restrict__ W1,
                                             const float* __restrict__ dinv,
                                             unsigned* __restrict__ hs, int n) {
#if HAS_MFMA
    const int lane = threadIdx.x & 63;
    const int wave = threadIdx.x >> 6;
    const int q4 = lane >> 4;
    const int l16 = lane & 15;
    half8 bfrag[4][4];
#pragma unroll
    for (int ks = 0; ks < 4; ++ks)
#pragma unroll
        for (int cb = 0; cb < 4; ++cb)
#pragma unroll
            for (int j = 0; j < 8; ++j)
                bfrag[ks][cb][j] =
                    (_Float16)W1[(ks * 32 + q4 * 8 + j) * HID_F + cb * 16 + l16];

    const int ntile = (n + 15) >> 4;
    for (int t = blockIdx.x * 4 + wave; t < ntile; t += gridDim.x * 4) {
        const int r0 = t << 4;
        const int arow = min(r0 + l16, n - 1);
        const float* xr = x + (size_t)arow * IN_F + q4 * 8;
        half8 afrag[4];
#pragma unroll
        for (int ks = 0; ks < 4; ++ks) {
            float4 v0 = *(const float4*)(xr + ks * 32);
            float4 v1 = *(const float4*)(xr + ks * 32 + 4);
            half8 a;
            a[0] = (_Float16)v0.x; a[1] = (_Float16)v0.y;
            a[2] = (_Float16)v0.z; a[3] = (_Float16)v0.w;
            a[4] = (_Float16)v1.x; a[5] = (_Float16)v1.y;
            a[6] = (_Float16)v1.z; a[7] = (_Float16)v1.w;
            afrag[ks] = a;
        }
        floatx4 acc[4] = {{0.f,0.f,0.f,0.f},{0.f,0.f,0.f,0.f},
                          {0.f,0.f,0.f,0.f},{0.f,0.f,0.f,0.f}};
#pragma unroll
        for (int ks = 0; ks < 4; ++ks) {
#pragma unroll
            for (int cb = 0; cb < 4; ++cb)
                acc[cb] = __builtin_amdgcn_mfma_f32_16x16x32_f16(
                    afrag[ks], bfrag[ks][cb], acc[cb], 0, 0, 0);
        }
        const int rbase = r0 + q4 * 4;
        float4 dvv = *(const float4*)(dinv + rbase);
        float dvr[4] = {dvv.x, dvv.y, dvv.z, dvv.w};
#pragma unroll
        for (int cb = 0; cb < 4; ++cb) {
#pragma unroll
            for (int reg = 0; reg < 4; ++reg) {
                float v = acc[cb][reg] * dvr[reg];
                float o = __shfl_xor(v, 1);
                if (!(l16 & 1)) {
                    int r = rbase + reg;
                    if (r < n)
                        hs[(size_t)r * 32 + cb * 8 + (l16 >> 1)] = f2h2(v, o);
                }
            }
        }
    }
#endif
}

// Grid-stride; each wave owns FOUR consecutive nodes with interleaved
// branchless gather chains (4 idx + 16 row gathers in flight per iter).
// Rows padded to %16.  fdot2 lane-extract accumulation, fp32.
#define ACC2(u, slo, shi) { slo = fdot2u(u, ONE_LO, slo); shi = fdot2u(u, ONE_HI, shi); }
template <int LAYER>
__global__ __launch_bounds__(256) void csr_agg(const int4* __restrict__ nodetab,
                                               const int* __restrict__ csr_src,
                                               const unsigned* __restrict__ hs,
                                               const float* __restrict__ bias,
                                               unsigned* __restrict__ hout, int n) {
    const int lane = threadIdx.x & 63;
    const int g = lane >> 4;          // edge slot 0..3
    const int w = lane & 15;          // feats 4w..4w+3
    const unsigned* __restrict__ hw = hs + 2 * w;
    const int STR = gridDim.x * 16;   // 4 waves/block x 4 nodes/wave
    const int SENT = n;

    for (int base = (blockIdx.x * 4 + (threadIdx.x >> 6)) * 4; base < n; base += STR) {
        int pp0, pp1, pp2, pp3, ee0, ee1, ee2, ee3;
        float dn0, dn1, dn2, dn3;
        {
            int4 nt0 = nodetab[base];
            pp0 = nt0.x; ee0 = nt0.y; dn0 = __int_as_float(nt0.z);
        }
        if (base + 1 < n) { int4 v = nodetab[base + 1]; pp1 = v.x; ee1 = v.y; dn1 = __int_as_float(v.z); }
        else { pp1 = 0; ee1 = 0; dn1 = 0.f; }
        if (base + 2 < n) { int4 v = nodetab[base + 2]; pp2 = v.x; ee2 = v.y; dn2 = __int_as_float(v.z); }
        else { pp2 = 0; ee2 = 0; dn2 = 0.f; }
        if (base + 3 < n) { int4 v = nodetab[base + 3]; pp3 = v.x; ee3 = v.y; dn3 = __int_as_float(v.z); }
        else { pp3 = 0; ee3 = 0; dn3 = 0.f; }

        float a00 = 0.f, a01 = 0.f, a02 = 0.f, a03 = 0.f;
        float a10 = 0.f, a11 = 0.f, a12 = 0.f, a13 = 0.f;
        float a20 = 0.f, a21 = 0.f, a22 = 0.f, a23 = 0.f;
        float a30 = 0.f, a31 = 0.f, a32 = 0.f, a33 = 0.f;
        if (g == 0) {                                      // self loops, once
            int s0 = base;
            int s1 = (base + 1 < n) ? base + 1 : SENT;
            int s2 = (base + 2 < n) ? base + 2 : SENT;
            int s3 = (base + 3 < n) ? base + 3 : SENT;
            uint2 u0 = *(const uint2*)(hw + (size_t)s0 * 32);
            uint2 u1 = *(const uint2*)(hw + (size_t)s1 * 32);
            uint2 u2 = *(const uint2*)(hw + (size_t)s2 * 32);
            uint2 u3 = *(const uint2*)(hw + (size_t)s3 * 32);
            ACC2(u0.x, a00, a01); ACC2(u0.y, a02, a03);
            ACC2(u1.x, a10, a11); ACC2(u1.y, a12, a13);
            ACC2(u2.x, a20, a21); ACC2(u2.y, a22, a23);
            ACC2(u3.x, a30, a31); ACC2(u3.y, a32, a33);
        }
        while ((pp0 < ee0) | (pp1 < ee1) | (pp2 < ee2) | (pp3 < ee3)) {
            int4 iv0 = (pp0 < ee0) ? *(const int4*)&csr_src[pp0 + 4 * g]
                                   : make_int4(SENT, SENT, SENT, SENT);
            int4 iv1 = (pp1 < ee1) ? *(const int4*)&csr_src[pp1 + 4 * g]
                                   : make_int4(SENT, SENT, SENT, SENT);
            int4 iv2 = (pp2 < ee2) ? *(const int4*)&csr_src[pp2 + 4 * g]
                                   : make_int4(SENT, SENT, SENT, SENT);
            int4 iv3 = (pp3 < ee3) ? *(const int4*)&csr_src[pp3 + 4 * g]
                                   : make_int4(SENT, SENT, SENT, SENT);
            uint2 u00 = *(const uint2*)(hw + (size_t)iv0.x * 32);
            uint2 u01 = *(const uint2*)(hw + (size_t)iv0.y * 32);
            uint2 u02 = *(const uint2*)(hw + (size_t)iv0.z * 32);
            uint2 u03 = *(const uint2*)(hw + (size_t)iv0.w * 32);
            uint2 u10 = *(const uint2*)(hw + (size_t)iv1.x * 32);
            uint2 u11 = *(const uint2*)(hw + (size_t)iv1.y * 32);
            uint2 u12 = *(const uint2*)(hw + (size_t)iv1.z * 32);
            uint2 u13 = *(const uint2*)(hw + (size_t)iv1.w * 32);
            uint2 u20 = *(const uint2*)(hw + (size_t)iv2.x * 32);
            uint2 u21 = *(const uint2*)(hw + (size_t)iv2.y * 32);
            uint2 u22 = *(const uint2*)(hw + (size_t)iv2.z * 32);
            uint2 u23 = *(const uint2*)(hw + (size_t)iv2.w * 32);
            uint2 u30 = *(const uint2*)(hw + (size_t)iv3.x * 32);
            uint2 u31 = *(const uint2*)(hw + (size_t)iv3.y * 32);
            uint2 u32 = *(const uint2*)(hw + (size_t)iv3.z * 32);
            uint2 u33 = *(const uint2*)(hw + (size_t)iv3.w * 32);
            ACC2(u00.x, a00, a01); ACC2(u00.y, a02, a03);
            ACC2(u01.x, a00, a01); ACC2(u01.y, a02, a03);
            ACC2(u02.x, a00, a01); ACC2(u02.y, a02, a03);
            ACC2(u03.x, a00, a01); ACC2(u03.y, a02, a03);
            ACC2(u10.x, a10, a11); ACC2(u10.y, a12, a13);
            ACC2(u11.x, a10, a11); ACC2(u11.y, a12, a13);
            ACC2(u12.x, a10, a11); ACC2(u12.y, a12, a13);
            ACC2(u13.x, a10, a11); ACC2(u13.y, a12, a13);
            ACC2(u20.x, a20, a21); ACC2(u20.y, a22, a23);
            ACC2(u21.x, a20, a21); ACC2(u21.y, a22, a23);
            ACC2(u22.x, a20, a21); ACC2(u22.y, a22, a23);
            ACC2(u23.x, a20, a21); ACC2(u23.y, a22, a23);
            ACC2(u30.x, a30, a31); ACC2(u30.y, a32, a33);
            ACC2(u31.x, a30, a31); ACC2(u31.y, a32, a33);
            ACC2(u32.x, a30, a31); ACC2(u32.y, a32, a33);
            ACC2(u33.x, a30, a31); ACC2(u33.y, a32, a33);
            pp0 += 16; pp1 += 16; pp2 += 16; pp3 += 16;
        }
        a00 += __shfl_xor(a00, 16); a00 += __shfl_xor(a00, 32);
        a01 += __shfl_xor(a01, 16); a01 += __shfl_xor(a01, 32);
        a02 += __shfl_xor(a02, 16); a02 += __shfl_xor(a02, 32);
        a03 += __shfl_xor(a03, 16); a03 += __shfl_xor(a03, 32);
        a10 += __shfl_xor(a10, 16); a10 += __shfl_xor(a10, 32);
        a11 += __shfl_xor(a11, 16); a11 += __shfl_xor(a11, 32);
        a12 += __shfl_xor(a12, 16); a12 += __shfl_xor(a12, 32);
        a13 += __shfl_xor(a13, 16); a13 += __shfl_xor(a13, 32);
        a20 += __shfl_xor(a20, 16); a20 += __shfl_xor(a20, 32);
        a21 += __shfl_xor(a21, 16); a21 += __shfl_xor(a21, 32);
        a22 += __shfl_xor(a22, 16); a22 += __shfl_xor(a22, 32);
        a23 += __shfl_xor(a23, 16); a23 += __shfl_xor(a23, 32);
        a30 += __shfl_xor(a30, 16); a30 += __shfl_xor(a30, 32);
        a31 += __shfl_xor(a31, 16); a31 += __shfl_xor(a31, 32);
        a32 += __shfl_xor(a32, 16); a32 += __shfl_xor(a32, 32);
        a33 += __shfl_xor(a33, 16); a33 += __shfl_xor(a33, 32);

        if (g == 0) {
            float4 bb;
            if (LAYER == 1) bb = *(const float4*)(bias + 4 * w);
#define EPI(i, dn, v0, v1, v2, v3)                                          \
            if (base + i < n) {                                             \
                float o0, o1, o2, o3;                                       \
                if (LAYER == 1) {                                           \
                    o0 = fmaxf(fmaf(dn, v0, bb.x), 0.f) * dn;               \
                    o1 = fmaxf(fmaf(dn, v1, bb.y), 0.f) * dn;               \
                    o2 = fmaxf(fmaf(dn, v2, bb.z), 0.f) * dn;               \
                    o3 = fmaxf(fmaf(dn, v3, bb.w), 0.f) * dn;               \
                } else {                                                    \
                    o0 = dn * v0; o1 = dn * v1; o2 = dn * v2; o3 = dn * v3; \
                }                                                           \
                uint2 ov;                                                   \
                ov.x = f2h2(o0, o1);                                        \
                ov.y = f2h2(o2, o3);                                        \
                *(uint2*)(hout + (size_t)(base + i) * 32 + 2 * w) = ov;     \
            }
            EPI(0, dn0, a00, a01, a02, a03)
            EPI(1, dn1, a10, a11, a12, a13)
            EPI(2, dn2, a20, a21, a22, a23)
            EPI(3, dn3, a30, a31, a32, a33)
#undef EPI
        }
    }
}

// out[n][96] = a2[n][64] @ W2[64][96] + b2.  MFMA: A = a2h rows (already
// fp16-packed in fragment order), B = W2 frags in registers (6 col-blocks).
__global__ __launch_bounds__(256) void gemm2(const unsigned* __restrict__ a2h,
                                             const float* __restrict__ W2,
                                             const float* __restrict__ b2,
                                             float* __restrict__ out, int n) {
#if HAS_MFMA
    const int lane = threadIdx.x & 63;
    const int wave = threadIdx.x >> 6;
    const int q4 = lane >> 4;
    const int l16 = lane & 15;
    half8 bfrag[2][6];
#pragma unroll
    for (int ks = 0; ks < 2; ++ks)
#pragma unroll
        for (int cb = 0; cb < 6; ++cb)
#pragma unroll
            for (int j = 0; j < 8; ++j)
                bfrag[ks][cb][j] =
                    (_Float16)W2[(ks * 32 + q4 * 8 + j) * OUT_F + cb * 16 + l16];
    float bb[6];
#pragma unroll
    for (int cb = 0; cb < 6; ++cb) bb[cb] = b2[cb * 16 + l16];

    const int ntile = (n + 15) >> 4;
    for (int t = blockIdx.x * 4 + wave; t < ntile; t += gridDim.x * 4) {
        const int r0 = t << 4;
        const int arow = min(r0 + l16, n - 1);
        const unsigned* ar = a2h + (size_t)arow * 32;
        half8 afrag[2];
#pragma unroll
        for (int ks = 0; ks < 2; ++ks) {
            uint4 v = *(const uint4*)(ar + ks * 16 + q4 * 4);
            afrag[ks] = __builtin_bit_cast(half8, v);
        }
        floatx4 acc[6] = {{0.f,0.f,0.f,0.f},{0.f,0.f,0.f,0.f},{0.f,0.f,0.f,0.f},
                          {0.f,0.f,0.f,0.f},{0.f,0.f,0.f,0.f},{0.f,0.f,0.f,0.f}};
#pragma unroll
        for (int ks = 0; ks < 2; ++ks) {
#pragma unroll
            for (int cb = 0; cb < 6; ++cb)
                acc[cb] = __builtin_amdgcn_mfma_f32_16x16x32_f16(
                    afrag[ks], bfrag[ks][cb], acc[cb], 0, 0, 0);
        }
        const int rbase = r0 + q4 * 4;
#pragma unroll
        for (int reg = 0; reg < 4; ++reg) {
            int r = rbase + reg;
            if (r < n) {
#pragma unroll
                for (int cb = 0; cb < 6; ++cb)
                    out[(size_t)r * OUT_F + cb * 16 + l16] = acc[cb][reg] + bb[cb];
            }
        }
    }
#endif
}

extern "C" void kernel_launch(void* const* d_in, const int* in_sizes, int n_in,
                              void* d_out, int out_size, void* d_ws, size_t ws_size,
                              hipStream_t stream) {
    const float* x  = (const float*)d_in[0];
    const int*   ei = (const int*)d_in[1];
    const float* W1 = (const float*)d_in[2];
    const float* b1 = (const float*)d_in[3];
    const float* W2 = (const float*)d_in[4];
    const float* b2 = (const float*)d_in[5];
    float* out = (float*)d_out;

    const int n = in_sizes[0] / IN_F;          // 100000
    const int E = in_sizes[1] / 2;             // 1600000
    const int* src = ei;
    const int* dst = ei + E;
    const int nbuck  = (n + 255) >> 8;         // 391
    const int nchunk = (E + CHUNK - 1) / CHUNK;// 391
    const int M = nbuck * nchunk;              // 152881
    const int NBS = (M + 1023) / 1024;
    const int g1tiles = (n + 15) / 16;         // 6250
    const int g1blocks = (g1tiles + 7) / 8;    // 782

    char* ws = (char*)d_ws;
    size_t off = 0;
    auto alloc = [&](size_t bytes) { void* p = ws + off; off = (off + bytes + 255) & ~(size_t)255; return p; };
    int*      hist    = (int*)alloc((size_t)M * 4);
    int*      offs    = (int*)alloc((size_t)M * 4);
    int*      bsum    = (int*)alloc(256 * 4);
    int*      boffs   = (int*)alloc(256 * 4);
    unsigned* part    = (unsigned*)alloc((size_t)E * 4);
    int*      csr_src = (int*)alloc(((size_t)E + (size_t)nbuck * 4096 + 64) * 4);
    int4*     nodetab = (int4*)alloc((size_t)n * 16);
    float*    dinv    = (float*)alloc((size_t)n * 4);
    unsigned* hs      = (unsigned*)alloc((size_t)(n + 1) * 32 * 4);
    unsigned* hs2     = (unsigned*)alloc((size_t)(n + 1) * 32 * 4);
    unsigned* a2h     = (unsigned*)alloc((size_t)n * 32 * 4);

    // CSR build: histogram -> scan -> partition -> per-bucket padded finalize
    init_sentinel<<<1, 64, 0, stream>>>(hs, hs2, n);
    hist_chunks <<<nchunk, 256, 0, stream>>>(dst, hist, E, nbuck, nchunk);
    scan_blocks <<<NBS, 256, 0, stream>>>(hist, offs, bsum, M);
    scan_bsums  <<<1, 256, 0, stream>>>(bsum, boffs, NBS);
    partition   <<<nchunk, 256, 0, stream>>>(src, dst, offs, boffs, part, E, nbuck, nchunk);
    build_bucket<<<nbuck, 256, 0, stream>>>(part, offs, boffs, csr_src, nodetab, dinv,
                                            n, E, nbuck, nchunk);

    // network
    gemm1      <<<g1blocks, 256, 0, stream>>>(x, W1, dinv, hs, n);
    csr_agg<1> <<<AGG_BLOCKS, 256, 0, stream>>>(nodetab, csr_src, hs, b1, hs2, n);
    csr_agg<2> <<<AGG_BLOCKS, 256, 0, stream>>>(nodetab, csr_src, hs2, NULL, a2h, n);
    gemm2      <<<g1blocks, 256, 0, stream>>>(a2h, W2, b2, out, n);
}

// Round 16
// 151.737 us; speedup vs baseline: 1.4961x; 1.0470x over previous
//
#include <hip/hip_runtime.h>
#include <hip/hip_fp16.h>

// ConformalGCN: 2-layer GCN, N=100000, E=1600000 (+self loops).
// R15: csr_agg back to 2-node interleave (R14's 4-node lost occupancy) with
//      8-lane uint4 row gathers: 1 gather instr = 8 distinct rows (2x addr
//      diversity), idx = one int2/lane per 16 edges. VMEM instrs/16edges
//      5 -> 3. gemm1/gemm2 MFMA (R13/R14, HW-verified) + radix CSR build.

#define IN_F  128
#define HID_F 64
#define OUT_F 96
#define CHUNK 4096
#define MAXB  12288         // stage capacity (padded bucket size), 48 KiB
#define AGG_BLOCKS 4096
#define ONE_LO 0x00003C00u  // fp16 (1.0, 0.0)
#define ONE_HI 0x3C000000u  // fp16 (0.0, 1.0)

typedef _Float16 f16x2 __attribute__((ext_vector_type(2)));
typedef _Float16 half8 __attribute__((ext_vector_type(8)));
typedef float floatx4 __attribute__((ext_vector_type(4)));

__device__ __forceinline__ float2 unpack2(unsigned u) {
    __half2 h = *reinterpret_cast<__half2*>(&u);
    return __half22float2(h);
}
__device__ __forceinline__ unsigned f2h2(float lo, float hi) {
    __half2 h = __floats2half2_rn(lo, hi);
    return *reinterpret_cast<unsigned*>(&h);
}

#if defined(__has_builtin)
#if __has_builtin(__builtin_amdgcn_fdot2)
#define HAS_FDOT2 1
#endif
#if __has_builtin(__builtin_amdgcn_mfma_f32_16x16x32_f16)
#define HAS_MFMA 1
#endif
#endif
#ifndef HAS_FDOT2
#define HAS_FDOT2 0
#endif
#ifndef HAS_MFMA
#define HAS_MFMA 0
#endif

__device__ __forceinline__ float fdot2u(unsigned a, unsigned b, float c) {
#if HAS_FDOT2
    return __builtin_amdgcn_fdot2(__builtin_bit_cast(f16x2, a),
                                  __builtin_bit_cast(f16x2, b), c, false);
#else
    float2 fa = unpack2(a), fb = unpack2(b);
    return fmaf(fa.y, fb.y, fmaf(fa.x, fb.x, c));
#endif
}

// zero the sentinel feature rows hs[n], hs2[n]
__global__ __launch_bounds__(64) void init_sentinel(unsigned* __restrict__ hs,
                                                    unsigned* __restrict__ hs2, int n) {
    int t = threadIdx.x;
    if (t < 32) {
        hs[(size_t)n * 32 + t] = 0u;
        hs2[(size_t)n * 32 + t] = 0u;
    }
}

// ---- pass 1a: per-chunk bucket histograms (bucket-major layout) ----
__global__ __launch_bounds__(256) void hist_chunks(const int* __restrict__ dst,
                                                   int* __restrict__ hist,
                                                   int E, int nbuck, int nchunk) {
    __shared__ int cnt[512];
    for (int i = threadIdx.x; i < nbuck; i += 256) cnt[i] = 0;
    __syncthreads();
    const int base = blockIdx.x * CHUNK;
    const int lim = min(base + CHUNK, E);
    for (int e = base + threadIdx.x; e < lim; e += 256)
        atomicAdd(&cnt[dst[e] >> 8], 1);
    __syncthreads();
    for (int b = threadIdx.x; b < nbuck; b += 256)
        hist[b * nchunk + blockIdx.x] = cnt[b];
}

// ---- hierarchical exclusive prefix sum (1024 elems/block) ----
__global__ __launch_bounds__(256) void scan_blocks(const int* __restrict__ in,
                                                   int* __restrict__ pre,
                                                   int* __restrict__ bsum, int m) {
    __shared__ int lds[256];
    const int t = threadIdx.x;
    const int base = blockIdx.x * 1024 + t * 4;
    int v0 = (base + 0 < m) ? in[base + 0] : 0;
    int v1 = (base + 1 < m) ? in[base + 1] : 0;
    int v2 = (base + 2 < m) ? in[base + 2] : 0;
    int v3 = (base + 3 < m) ? in[base + 3] : 0;
    int s = v0 + v1 + v2 + v3;
    lds[t] = s;
    __syncthreads();
    for (int off = 1; off < 256; off <<= 1) {
        int add = (t >= off) ? lds[t - off] : 0;
        __syncthreads();
        lds[t] += add;
        __syncthreads();
    }
    int e = lds[t] - s;
    if (base + 0 < m) pre[base + 0] = e;
    e += v0;
    if (base + 1 < m) pre[base + 1] = e;
    e += v1;
    if (base + 2 < m) pre[base + 2] = e;
    e += v2;
    if (base + 3 < m) pre[base + 3] = e;
    if (t == 255) bsum[blockIdx.x] = lds[255];
}

__global__ __launch_bounds__(256) void scan_bsums(const int* __restrict__ bsum,
                                                  int* __restrict__ boffs, int nb) {
    __shared__ int lds[256];
    const int t = threadIdx.x;
    int v = (t < nb) ? bsum[t] : 0;
    lds[t] = v;
    __syncthreads();
    for (int off = 1; off < 256; off <<= 1) {
        int add = (t >= off) ? lds[t - off] : 0;
        __syncthreads();
        lds[t] += add;
        __syncthreads();
    }
    boffs[t] = lds[t] - v;
}

// ---- pass 1b: partition edges into bucket-grouped runs, 4B records ----
__global__ __launch_bounds__(256) void partition(const int* __restrict__ src,
                                                 const int* __restrict__ dst,
                                                 const int* __restrict__ offs,
                                                 const int* __restrict__ boffs,
                                                 unsigned* __restrict__ part,
                                                 int E, int nbuck, int nchunk) {
    __shared__ int off[512];
    for (int b = threadIdx.x; b < nbuck; b += 256) {
        int idx = b * nchunk + blockIdx.x;
        off[b] = offs[idx] + boffs[idx >> 10];
    }
    __syncthreads();
    const int base = blockIdx.x * CHUNK;
    const int lim = min(base + CHUNK, E);
    for (int e = base + threadIdx.x; e < lim; e += 256) {
        int d = dst[e], s = src[e];
        int pos = atomicAdd(&off[d >> 8], 1);
        part[pos] = ((unsigned)s << 8) | (unsigned)(d & 255);
    }
}

// ---- pass 2: per-bucket padded CSR finalize ----
__global__ __launch_bounds__(256) void build_bucket(const unsigned* __restrict__ part,
                                                    const int* __restrict__ offs,
                                                    const int* __restrict__ boffs,
                                                    int* __restrict__ csr_src,
                                                    int4* __restrict__ nodetab,
                                                    float* __restrict__ dinv,
                                                    int n, int E, int nbuck, int nchunk) {
    __shared__ int cnt[256], sc[256], off[256];
    __shared__ int stage[MAXB];
    const int b = blockIdx.x;
    const int t = threadIdx.x;
    const int i0 = b * nchunk;
    const int bstart = offs[i0] + boffs[i0 >> 10];
    int bend = E;
    if (b + 1 < nbuck) {
        const int i1 = (b + 1) * nchunk;
        bend = offs[i1] + boffs[i1 >> 10];
    }
    const int bstart_pad = bstart + b * 4096;
    const int nodebase = b << 8;
    const int nnodes = min(256, n - nodebase);

    cnt[t] = 0;
    __syncthreads();
    for (int i = bstart + t; i < bend; i += 256)
        atomicAdd(&cnt[part[i] & 255u], 1);
    __syncthreads();
    const int deg = cnt[t];
    const int pdeg = (deg + 15) & ~15;
    sc[t] = pdeg;
    __syncthreads();
    for (int o = 1; o < 256; o <<= 1) {
        int add = (t >= o) ? sc[t - o] : 0;
        __syncthreads();
        sc[t] += add;
        __syncthreads();
    }
    const int pexcl = sc[t] - pdeg;
    const int psize = sc[255];
    if (t < nnodes) {
        float dv = rsqrtf((float)(deg + 1));   // +1 self loop
        nodetab[nodebase + t] = make_int4(bstart_pad + pexcl,
                                          bstart_pad + pexcl + pdeg,
                                          __float_as_int(dv), 0);
        dinv[nodebase + t] = dv;
    }
    off[t] = pexcl;
    __syncthreads();

    if (psize <= MAXB) {
        for (int i = t; i < psize; i += 256) stage[i] = n;   // sentinel fill
        __syncthreads();
        for (int i = bstart + t; i < bend; i += 256) {
            unsigned r = part[i];
            int pos = atomicAdd(&off[r & 255u], 1);
            stage[pos] = (int)(r >> 8);
        }
        __syncthreads();
        for (int i = t; i < psize; i += 256)
            csr_src[bstart_pad + i] = stage[i];
    } else {   // safety fallback
        for (int i = t; i < psize; i += 256) csr_src[bstart_pad + i] = n;
        __syncthreads();
        for (int i = bstart + t; i < bend; i += 256) {
            unsigned r = part[i];
            int pos = atomicAdd(&off[r & 255u], 1);
            csr_src[bstart_pad + pos] = (int)(r >> 8);
        }
    }
}

// hs[row] = fp16x2( dinv[row] * (x[row] @ W1) ).  MFMA (R13, HW-verified).
__global__ __launch_bounds__(256) void gemm1(const float* __restrict__ x,
                                             const float* __restrict__ W1,
                                             const float* __restrict__ dinv,
                                             unsigned* __restrict__ hs, int n) {
#if HAS_MFMA
    const int lane = threadIdx.x & 63;
    const int wave = threadIdx.x >> 6;
    const int q4 = lane >> 4;
    const int l16 = lane & 15;
    half8 bfrag[4][4];
#pragma unroll
    for (int ks = 0; ks < 4; ++ks)
#pragma unroll
        for (int cb = 0; cb < 4; ++cb)
#pragma unroll
            for (int j = 0; j < 8; ++j)
                bfrag[ks][cb][j] =
                    (_Float16)W1[(ks * 32 + q4 * 8 + j) * HID_F + cb * 16 + l16];

    const int ntile = (n + 15) >> 4;
    for (int t = blockIdx.x * 4 + wave; t < ntile; t += gridDim.x * 4) {
        const int r0 = t << 4;
        const int arow = min(r0 + l16, n - 1);
        const float* xr = x + (size_t)arow * IN_F + q4 * 8;
        half8 afrag[4];
#pragma unroll
        for (int ks = 0; ks < 4; ++ks) {
            float4 v0 = *(const float4*)(xr + ks * 32);
            float4 v1 = *(const float4*)(xr + ks * 32 + 4);
            half8 a;
            a[0] = (_Float16)v0.x; a[1] = (_Float16)v0.y;
            a[2] = (_Float16)v0.z; a[3] = (_Float16)v0.w;
            a[4] = (_Float16)v1.x; a[5] = (_Float16)v1.y;
            a[6] = (_Float16)v1.z; a[7] = (_Float16)v1.w;
            afrag[ks] = a;
        }
        floatx4 acc[4] = {{0.f,0.f,0.f,0.f},{0.f,0.f,0.f,0.f},
                          {0.f,0.f,0.f,0.f},{0.f,0.f,0.f,0.f}};
#pragma unroll
        for (int ks = 0; ks < 4; ++ks) {
#pragma unroll
            for (int cb = 0; cb < 4; ++cb)
                acc[cb] = __builtin_amdgcn_mfma_f32_16x16x32_f16(
                    afrag[ks], bfrag[ks][cb], acc[cb], 0, 0, 0);
        }
        const int rbase = r0 + q4 * 4;
        float4 dvv = *(const float4*)(dinv + rbase);
        float dvr[4] = {dvv.x, dvv.y, dvv.z, dvv.w};
#pragma unroll
        for (int cb = 0; cb < 4; ++cb) {
#pragma unroll
            for (int reg = 0; reg < 4; ++reg) {
                float v = acc[cb][reg] * dvr[reg];
                float o = __shfl_xor(v, 1);
                if (!(l16 & 1)) {
                    int r = rbase + reg;
                    if (r < n)
                        hs[(size_t)r * 32 + cb * 8 + (l16 >> 1)] = f2h2(v, o);
                }
            }
        }
    }
#endif
}

// Grid-stride; each wave owns TWO consecutive nodes, interleaved branchless
// chains.  8-lane row groups: slot g=lane>>3 owns edges (2g,2g+1) per
// 16-edge block via one int2 idx load; lane w=lane&7 holds feats 8w..8w+7
// as uint4 -> one gather instr = 8 distinct rows.  Rows padded %16.
#define ACC2(u, slo, shi) { slo = fdot2u(u, ONE_LO, slo); shi = fdot2u(u, ONE_HI, shi); }
template <int LAYER>
__global__ __launch_bounds__(256) void csr_agg(const int4* __restrict__ nodetab,
                                               const int* __restrict__ csr_src,
                                               const unsigned* __restrict__ hs,
                                               const float* __restrict__ bias,
                                               unsigned* __restrict__ hout, int n) {
    const int lane = threadIdx.x & 63;
    const int g = lane >> 3;          // edge slot 0..7
    const int w = lane & 7;           // feats 8w..8w+7 (uint4 #w of row)
    const uint4* __restrict__ hw4 = (const uint4*)hs + w;   // row = 8 uint4
    const int STR = gridDim.x * 8;
    const int SENT = n;

    int nodeA = (blockIdx.x * 4 + (threadIdx.x >> 6)) * 2;
    if (nodeA >= n) return;
    int4 ntA = nodetab[nodeA];
    bool hasB = nodeA + 1 < n;
    int4 ntB = hasB ? nodetab[nodeA + 1] : make_int4(0, 0, 0, 0);

    for (;;) {
        const int nxt = nodeA + STR;
        const bool more = nxt < n;
        int4 ntA_n, ntB_n;
        bool hasB_n = false;
        if (more) {
            ntA_n = nodetab[nxt];
            hasB_n = nxt + 1 < n;
            if (hasB_n) ntB_n = nodetab[nxt + 1];
        }

        int pA = ntA.x;
        const int endA = ntA.y;
        const float dnA = __int_as_float(ntA.z);
        int pB = hasB ? ntB.x : 0;
        const int endB = hasB ? ntB.y : 0;
        const float dnB = hasB ? __int_as_float(ntB.z) : 0.f;

        float aA0 = 0.f, aA1 = 0.f, aA2 = 0.f, aA3 = 0.f;
        float aA4 = 0.f, aA5 = 0.f, aA6 = 0.f, aA7 = 0.f;
        float aB0 = 0.f, aB1 = 0.f, aB2 = 0.f, aB3 = 0.f;
        float aB4 = 0.f, aB5 = 0.f, aB6 = 0.f, aB7 = 0.f;
        if (g == 0) {                                      // self loops, once
            uint4 suA = hw4[(size_t)nodeA * 8];
            ACC2(suA.x, aA0, aA1); ACC2(suA.y, aA2, aA3);
            ACC2(suA.z, aA4, aA5); ACC2(suA.w, aA6, aA7);
            if (hasB) {
                uint4 suB = hw4[(size_t)(nodeA + 1) * 8];
                ACC2(suB.x, aB0, aB1); ACC2(suB.y, aB2, aB3);
                ACC2(suB.z, aB4, aB5); ACC2(suB.w, aB6, aB7);
            }
        }
        while (pA < endA || pB < endB) {
            int2 ivA = (pA < endA) ? *(const int2*)&csr_src[pA + 2 * g]
                                   : make_int2(SENT, SENT);
            int2 ivB = (pB < endB) ? *(const int2*)&csr_src[pB + 2 * g]
                                   : make_int2(SENT, SENT);
            uint4 uA0 = hw4[(size_t)ivA.x * 8];
            uint4 uA1 = hw4[(size_t)ivA.y * 8];
            uint4 uB0 = hw4[(size_t)ivB.x * 8];
            uint4 uB1 = hw4[(size_t)ivB.y * 8];
            ACC2(uA0.x, aA0, aA1); ACC2(uA0.y, aA2, aA3);
            ACC2(uA0.z, aA4, aA5); ACC2(uA0.w, aA6, aA7);
            ACC2(uA1.x, aA0, aA1); ACC2(uA1.y, aA2, aA3);
            ACC2(uA1.z, aA4, aA5); ACC2(uA1.w, aA6, aA7);
            ACC2(uB0.x, aB0, aB1); ACC2(uB0.y, aB2, aB3);
            ACC2(uB0.z, aB4, aB5); ACC2(uB0.w, aB6, aB7);
            ACC2(uB1.x, aB0, aB1); ACC2(uB1.y, aB2, aB3);
            ACC2(uB1.z, aB4, aB5); ACC2(uB1.w, aB6, aB7);
            pA += 16; pB += 16;
        }
        // reduce across the 8 slots (lanes with same w, xor 8/16/32)
        aA0 += __shfl_xor(aA0, 8); aA0 += __shfl_xor(aA0, 16); aA0 += __shfl_xor(aA0, 32);
        aA1 += __shfl_xor(aA1, 8); aA1 += __shfl_xor(aA1, 16); aA1 += __shfl_xor(aA1, 32);
        aA2 += __shfl_xor(aA2, 8); aA2 += __shfl_xor(aA2, 16); aA2 += __shfl_xor(aA2, 32);
        aA3 += __shfl_xor(aA3, 8); aA3 += __shfl_xor(aA3, 16); aA3 += __shfl_xor(aA3, 32);
        aA4 += __shfl_xor(aA4, 8); aA4 += __shfl_xor(aA4, 16); aA4 += __shfl_xor(aA4, 32);
        aA5 += __shfl_xor(aA5, 8); aA5 += __shfl_xor(aA5, 16); aA5 += __shfl_xor(aA5, 32);
        aA6 += __shfl_xor(aA6, 8); aA6 += __shfl_xor(aA6, 16); aA6 += __shfl_xor(aA6, 32);
        aA7 += __shfl_xor(aA7, 8); aA7 += __shfl_xor(aA7, 16); aA7 += __shfl_xor(aA7, 32);
        aB0 += __shfl_xor(aB0, 8); aB0 += __shfl_xor(aB0, 16); aB0 += __shfl_xor(aB0, 32);
        aB1 += __shfl_xor(aB1, 8); aB1 += __shfl_xor(aB1, 16); aB1 += __shfl_xor(aB1, 32);
        aB2 += __shfl_xor(aB2, 8); aB2 += __shfl_xor(aB2, 16); aB2 += __shfl_xor(aB2, 32);
        aB3 += __shfl_xor(aB3, 8); aB3 += __shfl_xor(aB3, 16); aB3 += __shfl_xor(aB3, 32);
        aB4 += __shfl_xor(aB4, 8); aB4 += __shfl_xor(aB4, 16); aB4 += __shfl_xor(aB4, 32);
        aB5 += __shfl_xor(aB5, 8); aB5 += __shfl_xor(aB5, 16); aB5 += __shfl_xor(aB5, 32);
        aB6 += __shfl_xor(aB6, 8); aB6 += __shfl_xor(aB6, 16); aB6 += __shfl_xor(aB6, 32);
        aB7 += __shfl_xor(aB7, 8); aB7 += __shfl_xor(aB7, 16); aB7 += __shfl_xor(aB7, 32);

        if (g == 0) {
            float4 bb0, bb1;
            if (LAYER == 1) {
                bb0 = *(const float4*)(bias + 8 * w);
                bb1 = *(const float4*)(bias + 8 * w + 4);
            }
            float o0, o1, o2, o3, o4, o5, o6, o7;
            if (LAYER == 1) {
                o0 = fmaxf(fmaf(dnA, aA0, bb0.x), 0.f) * dnA;
                o1 = fmaxf(fmaf(dnA, aA1, bb0.y), 0.f) * dnA;
                o2 = fmaxf(fmaf(dnA, aA2, bb0.z), 0.f) * dnA;
                o3 = fmaxf(fmaf(dnA, aA3, bb0.w), 0.f) * dnA;
                o4 = fmaxf(fmaf(dnA, aA4, bb1.x), 0.f) * dnA;
                o5 = fmaxf(fmaf(dnA, aA5, bb1.y), 0.f) * dnA;
                o6 = fmaxf(fmaf(dnA, aA6, bb1.z), 0.f) * dnA;
                o7 = fmaxf(fmaf(dnA, aA7, bb1.w), 0.f) * dnA;
            } else {
                o0 = dnA * aA0; o1 = dnA * aA1; o2 = dnA * aA2; o3 = dnA * aA3;
                o4 = dnA * aA4; o5 = dnA * aA5; o6 = dnA * aA6; o7 = dnA * aA7;
            }
            uint4 ov;
            ov.x = f2h2(o0, o1); ov.y = f2h2(o2, o3);
            ov.z = f2h2(o4, o5); ov.w = f2h2(o6, o7);
            *(uint4*)(hout + (size_t)nodeA * 32 + 4 * w) = ov;
            if (hasB) {
                if (LAYER == 1) {
                    o0 = fmaxf(fmaf(dnB, aB0, bb0.x), 0.f) * dnB;
                    o1 = fmaxf(fmaf(dnB, aB1, bb0.y), 0.f) * dnB;
                    o2 = fmaxf(fmaf(dnB, aB2, bb0.z), 0.f) * dnB;
                    o3 = fmaxf(fmaf(dnB, aB3, bb0.w), 0.f) * dnB;
                    o4 = fmaxf(fmaf(dnB, aB4, bb1.x), 0.f) * dnB;
                    o5 = fmaxf(fmaf(dnB, aB5, bb1.y), 0.f) * dnB;
                    o6 = fmaxf(fmaf(dnB, aB6, bb1.z), 0.f) * dnB;
                    o7 = fmaxf(fmaf(dnB, aB7, bb1.w), 0.f) * dnB;
                } else {
                    o0 = dnB * aB0; o1 = dnB * aB1; o2 = dnB * aB2; o3 = dnB * aB3;
                    o4 = dnB * aB4; o5 = dnB * aB5; o6 = dnB * aB6; o7 = dnB * aB7;
                }
                ov.x = f2h2(o0, o1); ov.y = f2h2(o2, o3);
                ov.z = f2h2(o4, o5); ov.w = f2h2(o6, o7);
                *(uint4*)(hout + (size_t)(nodeA + 1) * 32 + 4 * w) = ov;
            }
        }
        if (!more) break;
        nodeA = nxt;
        ntA = ntA_n;
        hasB = hasB_n;
        ntB = ntB_n;
    }
}

// out[n][96] = a2[n][64] @ W2[64][96] + b2.  MFMA (R14, HW-verified).
__global__ __launch_bounds__(256) void gemm2(const unsigned* __restrict__ a2h,
                                             const float* __restrict__ W2,
                                             const float* __restrict__ b2,
                                             float* __restrict__ out, int n) {
#if HAS_MFMA
    const int lane = threadIdx.x & 63;
    const int wave = threadIdx.x >> 6;
    const int q4 = lane >> 4;
    const int l16 = lane & 15;
    half8 bfrag[2][6];
#pragma unroll
    for (int ks = 0; ks < 2; ++ks)
#pragma unroll
        for (int cb = 0; cb < 6; ++cb)
#pragma unroll
            for (int j = 0; j < 8; ++j)
                bfrag[ks][cb][j] =
                    (_Float16)W2[(ks * 32 + q4 * 8 + j) * OUT_F + cb * 16 + l16];
    float bb[6];
#pragma unroll
    for (int cb = 0; cb < 6; ++cb) bb[cb] = b2[cb * 16 + l16];

    const int ntile = (n + 15) >> 4;
    for (int t = blockIdx.x * 4 + wave; t < ntile; t += gridDim.x * 4) {
        const int r0 = t << 4;
        const int arow = min(r0 + l16, n - 1);
        const unsigned* ar = a2h + (size_t)arow * 32;
        half8 afrag[2];
#pragma unroll
        for (int ks = 0; ks < 2; ++ks) {
            uint4 v = *(const uint4*)(ar + ks * 16 + q4 * 4);
            afrag[ks] = __builtin_bit_cast(half8, v);
        }
        floatx4 acc[6] = {{0.f,0.f,0.f,0.f},{0.f,0.f,0.f,0.f},{0.f,0.f,0.f,0.f},
                          {0.f,0.f,0.f,0.f},{0.f,0.f,0.f,0.f},{0.f,0.f,0.f,0.f}};
#pragma unroll
        for (int ks = 0; ks < 2; ++ks) {
#pragma unroll
            for (int cb = 0; cb < 6; ++cb)
                acc[cb] = __builtin_amdgcn_mfma_f32_16x16x32_f16(
                    afrag[ks], bfrag[ks][cb], acc[cb], 0, 0, 0);
        }
        const int rbase = r0 + q4 * 4;
#pragma unroll
        for (int reg = 0; reg < 4; ++reg) {
            int r = rbase + reg;
            if (r < n) {
#pragma unroll
                for (int cb = 0; cb < 6; ++cb)
                    out[(size_t)r * OUT_F + cb * 16 + l16] = acc[cb][reg] + bb[cb];
            }
        }
    }
#endif
}

extern "C" void kernel_launch(void* const* d_in, const int* in_sizes, int n_in,
                              void* d_out, int out_size, void* d_ws, size_t ws_size,
                              hipStream_t stream) {
    const float* x  = (const float*)d_in[0];
    const int*   ei = (const int*)d_in[1];
    const float* W1 = (const float*)d_in[2];
    const float* b1 = (const float*)d_in[3];
    const float* W2 = (const float*)d_in[4];
    const float* b2 = (const float*)d_in[5];
    float* out = (float*)d_out;

    const int n = in_sizes[0] / IN_F;          // 100000
    const int E = in_sizes[1] / 2;             // 1600000
    const int* src = ei;
    const int* dst = ei + E;
    const int nbuck  = (n + 255) >> 8;         // 391
    const int nchunk = (E + CHUNK - 1) / CHUNK;// 391
    const int M = nbuck * nchunk;              // 152881
    const int NBS = (M + 1023) / 1024;
    const int g1tiles = (n + 15) / 16;         // 6250
    const int g1blocks = (g1tiles + 7) / 8;    // 782

    char* ws = (char*)d_ws;
    size_t off = 0;
    auto alloc = [&](size_t bytes) { void* p = ws + off; off = (off + bytes + 255) & ~(size_t)255; return p; };
    int*      hist    = (int*)alloc((size_t)M * 4);
    int*      offs    = (int*)alloc((size_t)M * 4);
    int*      bsum    = (int*)alloc(256 * 4);
    int*      boffs   = (int*)alloc(256 * 4);
    unsigned* part    = (unsigned*)alloc((size_t)E * 4);
    int*      csr_src = (int*)alloc(((size_t)E + (size_t)nbuck * 4096 + 64) * 4);
    int4*     nodetab = (int4*)alloc((size_t)n * 16);
    float*    dinv    = (float*)alloc((size_t)n * 4);
    unsigned* hs      = (unsigned*)alloc((size_t)(n + 1) * 32 * 4);
    unsigned* hs2     = (unsigned*)alloc((size_t)(n + 1) * 32 * 4);
    unsigned* a2h     = (unsigned*)alloc((size_t)n * 32 * 4);

    // CSR build: histogram -> scan -> partition -> per-bucket padded finalize
    init_sentinel<<<1, 64, 0, stream>>>(hs, hs2, n);
    hist_chunks <<<nchunk, 256, 0, stream>>>(dst, hist, E, nbuck, nchunk);
    scan_blocks <<<NBS, 256, 0, stream>>>(hist, offs, bsum, M);
    scan_bsums  <<<1, 256, 0, stream>>>(bsum, boffs, NBS);
    partition   <<<nchunk, 256, 0, stream>>>(src, dst, offs, boffs, part, E, nbuck, nchunk);
    build_bucket<<<nbuck, 256, 0, stream>>>(part, offs, boffs, csr_src, nodetab, dinv,
                                            n, E, nbuck, nchunk);

    // network
    gemm1      <<<g1blocks, 256, 0, stream>>>(x, W1, dinv, hs, n);
    csr_agg<1> <<<AGG_BLOCKS, 256, 0, stream>>>(nodetab, csr_src, hs, b1, hs2, n);
    csr_agg<2> <<<AGG_BLOCKS, 256, 0, stream>>>(nodetab, csr_src, hs2, NULL, a2h, n);
    gemm2      <<<g1blocks, 256, 0, stream>>>(a2h, W2, b2, out, n);
}

// Round 17
// 149.387 us; speedup vs baseline: 1.5197x; 1.0157x over previous
//
#include <hip/hip_runtime.h>
#include <hip/hip_fp16.h>

// ConformalGCN: 2-layer GCN, N=100000, E=1600000 (+self loops).
// R16: csr_agg rows padded to %32 -> ~93% of nodes finish in ONE iteration
//      (1 int4 idx + 4 uint4 gathers per node, 10 loads in flight per wave);
//      bucket pad regions 128B-aligned; init_sentinel folded into scan_bsums.
//      FETCH is compulsory (8-XCD replication of hs, ~84MB) -> this targets
//      the last latency/issue slack. gemm1/gemm2 MFMA + radix CSR otherwise.

#define IN_F  128
#define HID_F 64
#define OUT_F 96
#define CHUNK 4096
#define MAXB  12288         // stage capacity (padded bucket size), 48 KiB
#define AGG_BLOCKS 4096
#define ONE_LO 0x00003C00u  // fp16 (1.0, 0.0)
#define ONE_HI 0x3C000000u  // fp16 (0.0, 1.0)

typedef _Float16 f16x2 __attribute__((ext_vector_type(2)));
typedef _Float16 half8 __attribute__((ext_vector_type(8)));
typedef float floatx4 __attribute__((ext_vector_type(4)));

__device__ __forceinline__ float2 unpack2(unsigned u) {
    __half2 h = *reinterpret_cast<__half2*>(&u);
    return __half22float2(h);
}
__device__ __forceinline__ unsigned f2h2(float lo, float hi) {
    __half2 h = __floats2half2_rn(lo, hi);
    return *reinterpret_cast<unsigned*>(&h);
}

#if defined(__has_builtin)
#if __has_builtin(__builtin_amdgcn_fdot2)
#define HAS_FDOT2 1
#endif
#if __has_builtin(__builtin_amdgcn_mfma_f32_16x16x32_f16)
#define HAS_MFMA 1
#endif
#endif
#ifndef HAS_FDOT2
#define HAS_FDOT2 0
#endif
#ifndef HAS_MFMA
#define HAS_MFMA 0
#endif

__device__ __forceinline__ float fdot2u(unsigned a, unsigned b, float c) {
#if HAS_FDOT2
    return __builtin_amdgcn_fdot2(__builtin_bit_cast(f16x2, a),
                                  __builtin_bit_cast(f16x2, b), c, false);
#else
    float2 fa = unpack2(a), fb = unpack2(b);
    return fmaf(fa.y, fb.y, fmaf(fa.x, fb.x, c));
#endif
}

// ---- pass 1a: per-chunk bucket histograms (bucket-major layout) ----
__global__ __launch_bounds__(256) void hist_chunks(const int* __restrict__ dst,
                                                   int* __restrict__ hist,
                                                   int E, int nbuck, int nchunk) {
    __shared__ int cnt[512];
    for (int i = threadIdx.x; i < nbuck; i += 256) cnt[i] = 0;
    __syncthreads();
    const int base = blockIdx.x * CHUNK;
    const int lim = min(base + CHUNK, E);
    for (int e = base + threadIdx.x; e < lim; e += 256)
        atomicAdd(&cnt[dst[e] >> 8], 1);
    __syncthreads();
    for (int b = threadIdx.x; b < nbuck; b += 256)
        hist[b * nchunk + blockIdx.x] = cnt[b];
}

// ---- hierarchical exclusive prefix sum (1024 elems/block) ----
__global__ __launch_bounds__(256) void scan_blocks(const int* __restrict__ in,
                                                   int* __restrict__ pre,
                                                   int* __restrict__ bsum, int m) {
    __shared__ int lds[256];
    const int t = threadIdx.x;
    const int base = blockIdx.x * 1024 + t * 4;
    int v0 = (base + 0 < m) ? in[base + 0] : 0;
    int v1 = (base + 1 < m) ? in[base + 1] : 0;
    int v2 = (base + 2 < m) ? in[base + 2] : 0;
    int v3 = (base + 3 < m) ? in[base + 3] : 0;
    int s = v0 + v1 + v2 + v3;
    lds[t] = s;
    __syncthreads();
    for (int off = 1; off < 256; off <<= 1) {
        int add = (t >= off) ? lds[t - off] : 0;
        __syncthreads();
        lds[t] += add;
        __syncthreads();
    }
    int e = lds[t] - s;
    if (base + 0 < m) pre[base + 0] = e;
    e += v0;
    if (base + 1 < m) pre[base + 1] = e;
    e += v1;
    if (base + 2 < m) pre[base + 2] = e;
    e += v2;
    if (base + 3 < m) pre[base + 3] = e;
    if (t == 255) bsum[blockIdx.x] = lds[255];
}

// scan of block sums + sentinel-row zeroing (folded init_sentinel)
__global__ __launch_bounds__(256) void scan_bsums(const int* __restrict__ bsum,
                                                  int* __restrict__ boffs, int nb,
                                                  unsigned* __restrict__ hs,
                                                  unsigned* __restrict__ hs2, int n) {
    __shared__ int lds[256];
    const int t = threadIdx.x;
    int v = (t < nb) ? bsum[t] : 0;
    lds[t] = v;
    __syncthreads();
    for (int off = 1; off < 256; off <<= 1) {
        int add = (t >= off) ? lds[t - off] : 0;
        __syncthreads();
        lds[t] += add;
        __syncthreads();
    }
    boffs[t] = lds[t] - v;
    if (t < 32) {
        hs[(size_t)n * 32 + t] = 0u;
        hs2[(size_t)n * 32 + t] = 0u;
    }
}

// ---- pass 1b: partition edges into bucket-grouped runs, 4B records ----
__global__ __launch_bounds__(256) void partition(const int* __restrict__ src,
                                                 const int* __restrict__ dst,
                                                 const int* __restrict__ offs,
                                                 const int* __restrict__ boffs,
                                                 unsigned* __restrict__ part,
                                                 int E, int nbuck, int nchunk) {
    __shared__ int off[512];
    for (int b = threadIdx.x; b < nbuck; b += 256) {
        int idx = b * nchunk + blockIdx.x;
        off[b] = offs[idx] + boffs[idx >> 10];
    }
    __syncthreads();
    const int base = blockIdx.x * CHUNK;
    const int lim = min(base + CHUNK, E);
    for (int e = base + threadIdx.x; e < lim; e += 256) {
        int d = dst[e], s = src[e];
        int pos = atomicAdd(&off[d >> 8], 1);
        part[pos] = ((unsigned)s << 8) | (unsigned)(d & 255);
    }
}

// ---- pass 2: per-bucket padded CSR finalize ----
// Row length padded to %32, sentinel src=n (zero row).  Bucket b's padded
// region starts at align128(bstart + b*8192) (max pad 256*31+31 < 8192).
__global__ __launch_bounds__(256) void build_bucket(const unsigned* __restrict__ part,
                                                    const int* __restrict__ offs,
                                                    const int* __restrict__ boffs,
                                                    int* __restrict__ csr_src,
                                                    int4* __restrict__ nodetab,
                                                    float* __restrict__ dinv,
                                                    int n, int E, int nbuck, int nchunk) {
    __shared__ int cnt[256], sc[256], off[256];
    __shared__ int stage[MAXB];
    const int b = blockIdx.x;
    const int t = threadIdx.x;
    const int i0 = b * nchunk;
    const int bstart = offs[i0] + boffs[i0 >> 10];
    int bend = E;
    if (b + 1 < nbuck) {
        const int i1 = (b + 1) * nchunk;
        bend = offs[i1] + boffs[i1 >> 10];
    }
    const int bstart_pad = (bstart + b * 8192 + 31) & ~31;   // 128B-aligned
    const int nodebase = b << 8;
    const int nnodes = min(256, n - nodebase);

    cnt[t] = 0;
    __syncthreads();
    for (int i = bstart + t; i < bend; i += 256)
        atomicAdd(&cnt[part[i] & 255u], 1);
    __syncthreads();
    const int deg = cnt[t];
    const int pdeg = (deg + 31) & ~31;
    sc[t] = pdeg;
    __syncthreads();
    for (int o = 1; o < 256; o <<= 1) {
        int add = (t >= o) ? sc[t - o] : 0;
        __syncthreads();
        sc[t] += add;
        __syncthreads();
    }
    const int pexcl = sc[t] - pdeg;
    const int psize = sc[255];
    if (t < nnodes) {
        float dv = rsqrtf((float)(deg + 1));   // +1 self loop
        nodetab[nodebase + t] = make_int4(bstart_pad + pexcl,
                                          bstart_pad + pexcl + pdeg,
                                          __float_as_int(dv), 0);
        dinv[nodebase + t] = dv;
    }
    off[t] = pexcl;
    __syncthreads();

    if (psize <= MAXB) {
        for (int i = t; i < psize; i += 256) stage[i] = n;   // sentinel fill
        __syncthreads();
        for (int i = bstart + t; i < bend; i += 256) {
            unsigned r = part[i];
            int pos = atomicAdd(&off[r & 255u], 1);
            stage[pos] = (int)(r >> 8);
        }
        __syncthreads();
        for (int i = t; i < psize; i += 256)
            csr_src[bstart_pad + i] = stage[i];
    } else {   // safety fallback
        for (int i = t; i < psize; i += 256) csr_src[bstart_pad + i] = n;
        __syncthreads();
        for (int i = bstart + t; i < bend; i += 256) {
            unsigned r = part[i];
            int pos = atomicAdd(&off[r & 255u], 1);
            csr_src[bstart_pad + pos] = (int)(r >> 8);
        }
    }
}

// hs[row] = fp16x2( dinv[row] * (x[row] @ W1) ).  MFMA (R13, HW-verified).
__global__ __launch_bounds__(256) void gemm1(const float* __restrict__ x,
                                             const float* __restrict__ W1,
                                             const float* __restrict__ dinv,
                                             unsigned* __restrict__ hs, int n) {
#if HAS_MFMA
    const int lane = threadIdx.x & 63;
    const int wave = threadIdx.x >> 6;
    const int q4 = lane >> 4;
    const int l16 = lane & 15;
    half8 bfrag[4][4];
#pragma unroll
    for (int ks = 0; ks < 4; ++ks)
#pragma unroll
        for (int cb = 0; cb < 4; ++cb)
#pragma unroll
            for (int j = 0; j < 8; ++j)
                bfrag[ks][cb][j] =
                    (_Float16)W1[(ks * 32 + q4 * 8 + j) * HID_F + cb * 16 + l16];

    const int ntile = (n + 15) >> 4;
    for (int t = blockIdx.x * 4 + wave; t < ntile; t += gridDim.x * 4) {
        const int r0 = t << 4;
        const int arow = min(r0 + l16, n - 1);
        const float* xr = x + (size_t)arow * IN_F + q4 * 8;
        half8 afrag[4];
#pragma unroll
        for (int ks = 0; ks < 4; ++ks) {
            float4 v0 = *(const float4*)(xr + ks * 32);
            float4 v1 = *(const float4*)(xr + ks * 32 + 4);
            half8 a;
            a[0] = (_Float16)v0.x; a[1] = (_Float16)v0.y;
            a[2] = (_Float16)v0.z; a[3] = (_Float16)v0.w;
            a[4] = (_Float16)v1.x; a[5] = (_Float16)v1.y;
            a[6] = (_Float16)v1.z; a[7] = (_Float16)v1.w;
            afrag[ks] = a;
        }
        floatx4 acc[4] = {{0.f,0.f,0.f,0.f},{0.f,0.f,0.f,0.f},
                          {0.f,0.f,0.f,0.f},{0.f,0.f,0.f,0.f}};
#pragma unroll
        for (int ks = 0; ks < 4; ++ks) {
#pragma unroll
            for (int cb = 0; cb < 4; ++cb)
                acc[cb] = __builtin_amdgcn_mfma_f32_16x16x32_f16(
                    afrag[ks], bfrag[ks][cb], acc[cb], 0, 0, 0);
        }
        const int rbase = r0 + q4 * 4;
        float4 dvv = *(const float4*)(dinv + rbase);
        float dvr[4] = {dvv.x, dvv.y, dvv.z, dvv.w};
#pragma unroll
        for (int cb = 0; cb < 4; ++cb) {
#pragma unroll
            for (int reg = 0; reg < 4; ++reg) {
                float v = acc[cb][reg] * dvr[reg];
                float o = __shfl_xor(v, 1);
                if (!(l16 & 1)) {
                    int r = rbase + reg;
                    if (r < n)
                        hs[(size_t)r * 32 + cb * 8 + (l16 >> 1)] = f2h2(v, o);
                }
            }
        }
    }
#endif
}

// Grid-stride; each wave owns TWO consecutive nodes, interleaved branchless
// chains.  32 edges/node/iter: slot g=lane>>3 owns edges 4g..4g+3 via one
// int4 idx load; lane w=lane&7 holds feats 8w..8w+7 as uint4.  ~93% of
// nodes (deg<=32) finish in ONE iteration; 10 loads in flight per wave.
#define ACC2(u, slo, shi) { slo = fdot2u(u, ONE_LO, slo); shi = fdot2u(u, ONE_HI, shi); }
template <int LAYER>
__global__ __launch_bounds__(256) void csr_agg(const int4* __restrict__ nodetab,
                                               const int* __restrict__ csr_src,
                                               const unsigned* __restrict__ hs,
                                               const float* __restrict__ bias,
                                               unsigned* __restrict__ hout, int n) {
    const int lane = threadIdx.x & 63;
    const int g = lane >> 3;          // edge slot 0..7
    const int w = lane & 7;           // feats 8w..8w+7 (uint4 #w of row)
    const uint4* __restrict__ hw4 = (const uint4*)hs + w;   // row = 8 uint4
    const int STR = gridDim.x * 8;
    const int SENT = n;

    int nodeA = (blockIdx.x * 4 + (threadIdx.x >> 6)) * 2;
    if (nodeA >= n) return;
    int4 ntA = nodetab[nodeA];
    bool hasB = nodeA + 1 < n;
    int4 ntB = hasB ? nodetab[nodeA + 1] : make_int4(0, 0, 0, 0);

    for (;;) {
        const int nxt = nodeA + STR;
        const bool more = nxt < n;
        int4 ntA_n, ntB_n;
        bool hasB_n = false;
        if (more) {
            ntA_n = nodetab[nxt];
            hasB_n = nxt + 1 < n;
            if (hasB_n) ntB_n = nodetab[nxt + 1];
        }

        int pA = ntA.x;
        const int endA = ntA.y;
        const float dnA = __int_as_float(ntA.z);
        int pB = hasB ? ntB.x : 0;
        const int endB = hasB ? ntB.y : 0;
        const float dnB = hasB ? __int_as_float(ntB.z) : 0.f;

        float aA0 = 0.f, aA1 = 0.f, aA2 = 0.f, aA3 = 0.f;
        float aA4 = 0.f, aA5 = 0.f, aA6 = 0.f, aA7 = 0.f;
        float aB0 = 0.f, aB1 = 0.f, aB2 = 0.f, aB3 = 0.f;
        float aB4 = 0.f, aB5 = 0.f, aB6 = 0.f, aB7 = 0.f;
        if (g == 0) {                                      // self loops, once
            uint4 suA = hw4[(size_t)nodeA * 8];
            ACC2(suA.x, aA0, aA1); ACC2(suA.y, aA2, aA3);
            ACC2(suA.z, aA4, aA5); ACC2(suA.w, aA6, aA7);
            if (hasB) {
                uint4 suB = hw4[(size_t)(nodeA + 1) * 8];
                ACC2(suB.x, aB0, aB1); ACC2(suB.y, aB2, aB3);
                ACC2(suB.z, aB4, aB5); ACC2(suB.w, aB6, aB7);
            }
        }
        while (pA < endA || pB < endB) {
            int4 ivA = (pA < endA) ? *(const int4*)&csr_src[pA + 4 * g]
                                   : make_int4(SENT, SENT, SENT, SENT);
            int4 ivB = (pB < endB) ? *(const int4*)&csr_src[pB + 4 * g]
                                   : make_int4(SENT, SENT, SENT, SENT);
            uint4 uA0 = hw4[(size_t)ivA.x * 8];
            uint4 uA1 = hw4[(size_t)ivA.y * 8];
            uint4 uA2 = hw4[(size_t)ivA.z * 8];
            uint4 uA3 = hw4[(size_t)ivA.w * 8];
            uint4 uB0 = hw4[(size_t)ivB.x * 8];
            uint4 uB1 = hw4[(size_t)ivB.y * 8];
            uint4 uB2 = hw4[(size_t)ivB.z * 8];
            uint4 uB3 = hw4[(size_t)ivB.w * 8];
            ACC2(uA0.x, aA0, aA1); ACC2(uA0.y, aA2, aA3);
            ACC2(uA0.z, aA4, aA5); ACC2(uA0.w, aA6, aA7);
            ACC2(uA1.x, aA0, aA1); ACC2(uA1.y, aA2, aA3);
            ACC2(uA1.z, aA4, aA5); ACC2(uA1.w, aA6, aA7);
            ACC2(uA2.x, aA0, aA1); ACC2(uA2.y, aA2, aA3);
            ACC2(uA2.z, aA4, aA5); ACC2(uA2.w, aA6, aA7);
            ACC2(uA3.x, aA0, aA1); ACC2(uA3.y, aA2, aA3);
            ACC2(uA3.z, aA4, aA5); ACC2(uA3.w, aA6, aA7);
            ACC2(uB0.x, aB0, aB1); ACC2(uB0.y, aB2, aB3);
            ACC2(uB0.z, aB4, aB5); ACC2(uB0.w, aB6, aB7);
            ACC2(uB1.x, aB0, aB1); ACC2(uB1.y, aB2, aB3);
            ACC2(uB1.z, aB4, aB5); ACC2(uB1.w, aB6, aB7);
            ACC2(uB2.x, aB0, aB1); ACC2(uB2.y, aB2, aB3);
            ACC2(uB2.z, aB4, aB5); ACC2(uB2.w, aB6, aB7);
            ACC2(uB3.x, aB0, aB1); ACC2(uB3.y, aB2, aB3);
            ACC2(uB3.z, aB4, aB5); ACC2(uB3.w, aB6, aB7);
            pA += 32; pB += 32;
        }
        // reduce across the 8 slots (xor 8/16/32)
        aA0 += __shfl_xor(aA0, 8); aA0 += __shfl_xor(aA0, 16); aA0 += __shfl_xor(aA0, 32);
        aA1 += __shfl_xor(aA1, 8); aA1 += __shfl_xor(aA1, 16); aA1 += __shfl_xor(aA1, 32);
        aA2 += __shfl_xor(aA2, 8); aA2 += __shfl_xor(aA2, 16); aA2 += __shfl_xor(aA2, 32);
        aA3 += __shfl_xor(aA3, 8); aA3 += __shfl_xor(aA3, 16); aA3 += __shfl_xor(aA3, 32);
        aA4 += __shfl_xor(aA4, 8); aA4 += __shfl_xor(aA4, 16); aA4 += __shfl_xor(aA4, 32);
        aA5 += __shfl_xor(aA5, 8); aA5 += __shfl_xor(aA5, 16); aA5 += __shfl_xor(aA5, 32);
        aA6 += __shfl_xor(aA6, 8); aA6 += __shfl_xor(aA6, 16); aA6 += __shfl_xor(aA6, 32);
        aA7 += __shfl_xor(aA7, 8); aA7 += __shfl_xor(aA7, 16); aA7 += __shfl_xor(aA7, 32);
        aB0 += __shfl_xor(aB0, 8); aB0 += __shfl_xor(aB0, 16); aB0 += __shfl_xor(aB0, 32);
        aB1 += __shfl_xor(aB1, 8); aB1 += __shfl_xor(aB1, 16); aB1 += __shfl_xor(aB1, 32);
        aB2 += __shfl_xor(aB2, 8); aB2 += __shfl_xor(aB2, 16); aB2 += __shfl_xor(aB2, 32);
        aB3 += __shfl_xor(aB3, 8); aB3 += __shfl_xor(aB3, 16); aB3 += __shfl_xor(aB3, 32);
        aB4 += __shfl_xor(aB4, 8); aB4 += __shfl_xor(aB4, 16); aB4 += __shfl_xor(aB4, 32);
        aB5 += __shfl_xor(aB5, 8); aB5 += __shfl_xor(aB5, 16); aB5 += __shfl_xor(aB5, 32);
        aB6 += __shfl_xor(aB6, 8); aB6 += __shfl_xor(aB6, 16); aB6 += __shfl_xor(aB6, 32);
        aB7 += __shfl_xor(aB7, 8); aB7 += __shfl_xor(aB7, 16); aB7 += __shfl_xor(aB7, 32);

        if (g == 0) {
            float4 bb0, bb1;
            if (LAYER == 1) {
                bb0 = *(const float4*)(bias + 8 * w);
                bb1 = *(const float4*)(bias + 8 * w + 4);
            }
            float o0, o1, o2, o3, o4, o5, o6, o7;
            if (LAYER == 1) {
                o0 = fmaxf(fmaf(dnA, aA0, bb0.x), 0.f) * dnA;
                o1 = fmaxf(fmaf(dnA, aA1, bb0.y), 0.f) * dnA;
                o2 = fmaxf(fmaf(dnA, aA2, bb0.z), 0.f) * dnA;
                o3 = fmaxf(fmaf(dnA, aA3, bb0.w), 0.f) * dnA;
                o4 = fmaxf(fmaf(dnA, aA4, bb1.x), 0.f) * dnA;
                o5 = fmaxf(fmaf(dnA, aA5, bb1.y), 0.f) * dnA;
                o6 = fmaxf(fmaf(dnA, aA6, bb1.z), 0.f) * dnA;
                o7 = fmaxf(fmaf(dnA, aA7, bb1.w), 0.f) * dnA;
            } else {
                o0 = dnA * aA0; o1 = dnA * aA1; o2 = dnA * aA2; o3 = dnA * aA3;
                o4 = dnA * aA4; o5 = dnA * aA5; o6 = dnA * aA6; o7 = dnA * aA7;
            }
            uint4 ov;
            ov.x = f2h2(o0, o1); ov.y = f2h2(o2, o3);
            ov.z = f2h2(o4, o5); ov.w = f2h2(o6, o7);
            *(uint4*)(hout + (size_t)nodeA * 32 + 4 * w) = ov;
            if (hasB) {
                if (LAYER == 1) {
                    o0 = fmaxf(fmaf(dnB, aB0, bb0.x), 0.f) * dnB;
                    o1 = fmaxf(fmaf(dnB, aB1, bb0.y), 0.f) * dnB;
                    o2 = fmaxf(fmaf(dnB, aB2, bb0.z), 0.f) * dnB;
                    o3 = fmaxf(fmaf(dnB, aB3, bb0.w), 0.f) * dnB;
                    o4 = fmaxf(fmaf(dnB, aB4, bb1.x), 0.f) * dnB;
                    o5 = fmaxf(fmaf(dnB, aB5, bb1.y), 0.f) * dnB;
                    o6 = fmaxf(fmaf(dnB, aB6, bb1.z), 0.f) * dnB;
                    o7 = fmaxf(fmaf(dnB, aB7, bb1.w), 0.f) * dnB;
                } else {
                    o0 = dnB * aB0; o1 = dnB * aB1; o2 = dnB * aB2; o3 = dnB * aB3;
                    o4 = dnB * aB4; o5 = dnB * aB5; o6 = dnB * aB6; o7 = dnB * aB7;
                }
                ov.x = f2h2(o0, o1); ov.y = f2h2(o2, o3);
                ov.z = f2h2(o4, o5); ov.w = f2h2(o6, o7);
                *(uint4*)(hout + (size_t)(nodeA + 1) * 32 + 4 * w) = ov;
            }
        }
        if (!more) break;
        nodeA = nxt;
        ntA = ntA_n;
        hasB = hasB_n;
        ntB = ntB_n;
    }
}

// out[n][96] = a2[n][64] @ W2[64][96] + b2.  MFMA (R14, HW-verified).
__global__ __launch_bounds__(256) void gemm2(const unsigned* __restrict__ a2h,
                                             const float* __restrict__ W2,
                                             const float* __restrict__ b2,
                                             float* __restrict__ out, int n) {
#if HAS_MFMA
    const int lane = threadIdx.x & 63;
    const int wave = threadIdx.x >> 6;
    const int q4 = lane >> 4;
    const int l16 = lane & 15;
    half8 bfrag[2][6];
#pragma unroll
    for (int ks = 0; ks < 2; ++ks)
#pragma unroll
        for (int cb = 0; cb < 6; ++cb)
#pragma unroll
            for (int j = 0; j < 8; ++j)
                bfrag[ks][cb][j] =
                    (_Float16)W2[(ks * 32 + q4 * 8 + j) * OUT_F + cb * 16 + l16];
    float bb[6];
#pragma unroll
    for (int cb = 0; cb < 6; ++cb) bb[cb] = b2[cb * 16 + l16];

    const int ntile = (n + 15) >> 4;
    for (int t = blockIdx.x * 4 + wave; t < ntile; t += gridDim.x * 4) {
        const int r0 = t << 4;
        const int arow = min(r0 + l16, n - 1);
        const unsigned* ar = a2h + (size_t)arow * 32;
        half8 afrag[2];
#pragma unroll
        for (int ks = 0; ks < 2; ++ks) {
            uint4 v = *(const uint4*)(ar + ks * 16 + q4 * 4);
            afrag[ks] = __builtin_bit_cast(half8, v);
        }
        floatx4 acc[6] = {{0.f,0.f,0.f,0.f},{0.f,0.f,0.f,0.f},{0.f,0.f,0.f,0.f},
                          {0.f,0.f,0.f,0.f},{0.f,0.f,0.f,0.f},{0.f,0.f,0.f,0.f}};
#pragma unroll
        for (int ks = 0; ks < 2; ++ks) {
#pragma unroll
            for (int cb = 0; cb < 6; ++cb)
                acc[cb] = __builtin_amdgcn_mfma_f32_16x16x32_f16(
                    afrag[ks], bfrag[ks][cb], acc[cb], 0, 0, 0);
        }
        const int rbase = r0 + q4 * 4;
#pragma unroll
        for (int reg = 0; reg < 4; ++reg) {
            int r = rbase + reg;
            if (r < n) {
#pragma unroll
                for (int cb = 0; cb < 6; ++cb)
                    out[(size_t)r * OUT_F + cb * 16 + l16] = acc[cb][reg] + bb[cb];
            }
        }
    }
#endif
}

extern "C" void kernel_launch(void* const* d_in, const int* in_sizes, int n_in,
                              void* d_out, int out_size, void* d_ws, size_t ws_size,
                              hipStream_t stream) {
    const float* x  = (const float*)d_in[0];
    const int*   ei = (const int*)d_in[1];
    const float* W1 = (const float*)d_in[2];
    const float* b1 = (const float*)d_in[3];
    const float* W2 = (const float*)d_in[4];
    const float* b2 = (const float*)d_in[5];
    float* out = (float*)d_out;

    const int n = in_sizes[0] / IN_F;          // 100000
    const int E = in_sizes[1] / 2;             // 1600000
    const int* src = ei;
    const int* dst = ei + E;
    const int nbuck  = (n + 255) >> 8;         // 391
    const int nchunk = (E + CHUNK - 1) / CHUNK;// 391
    const int M = nbuck * nchunk;              // 152881
    const int NBS = (M + 1023) / 1024;
    const int g1tiles = (n + 15) / 16;         // 6250
    const int g1blocks = (g1tiles + 7) / 8;    // 782

    char* ws = (char*)d_ws;
    size_t off = 0;
    auto alloc = [&](size_t bytes) { void* p = ws + off; off = (off + bytes + 255) & ~(size_t)255; return p; };
    int*      hist    = (int*)alloc((size_t)M * 4);
    int*      offs    = (int*)alloc((size_t)M * 4);
    int*      bsum    = (int*)alloc(256 * 4);
    int*      boffs   = (int*)alloc(256 * 4);
    unsigned* part    = (unsigned*)alloc((size_t)E * 4);
    int*      csr_src = (int*)alloc(((size_t)E + (size_t)nbuck * 8192 + 128) * 4);
    int4*     nodetab = (int4*)alloc((size_t)n * 16);
    float*    dinv    = (float*)alloc((size_t)n * 4);
    unsigned* hs      = (unsigned*)alloc((size_t)(n + 1) * 32 * 4);
    unsigned* hs2     = (unsigned*)alloc((size_t)(n + 1) * 32 * 4);
    unsigned* a2h     = (unsigned*)alloc((size_t)n * 32 * 4);

    // CSR build: histogram -> scan (+sentinel init) -> partition -> finalize
    hist_chunks <<<nchunk, 256, 0, stream>>>(dst, hist, E, nbuck, nchunk);
    scan_blocks <<<NBS, 256, 0, stream>>>(hist, offs, bsum, M);
    scan_bsums  <<<1, 256, 0, stream>>>(bsum, boffs, NBS, hs, hs2, n);
    partition   <<<nchunk, 256, 0, stream>>>(src, dst, offs, boffs, part, E, nbuck, nchunk);
    build_bucket<<<nbuck, 256, 0, stream>>>(part, offs, boffs, csr_src, nodetab, dinv,
                                            n, E, nbuck, nchunk);

    // network
    gemm1      <<<g1blocks, 256, 0, stream>>>(x, W1, dinv, hs, n);
    csr_agg<1> <<<AGG_BLOCKS, 256, 0, stream>>>(nodetab, csr_src, hs, b1, hs2, n);
    csr_agg<2> <<<AGG_BLOCKS, 256, 0, stream>>>(nodetab, csr_src, hs2, NULL, a2h, n);
    gemm2      <<<g1blocks, 256, 0, stream>>>(a2h, W2, b2, out, n);
}

// Round 18
// 146.808 us; speedup vs baseline: 1.5464x; 1.0176x over previous
//
#include <hip/hip_runtime.h>
#include <hip/hip_fp16.h>

// ConformalGCN: 2-layer GCN, N=100000, E=1600000 (+self loops).
// R17: consolidation. csr_agg reverted to R15's measured-best geometry
//      (%16 padding, int2 idx, 8-lane uint4 gathers, 2-node interleave;
//      R16's %32 padding cost +3us of sentinel VALU work). Kept from R16:
//      folded sentinel-init, 128B-aligned bucket pad regions.
//      gemm1/gemm2 MFMA (HW-verified) + radix CSR build unchanged.

#define IN_F  128
#define HID_F 64
#define OUT_F 96
#define CHUNK 4096
#define MAXB  12288         // stage capacity (padded bucket size), 48 KiB
#define AGG_BLOCKS 4096
#define ONE_LO 0x00003C00u  // fp16 (1.0, 0.0)
#define ONE_HI 0x3C000000u  // fp16 (0.0, 1.0)

typedef _Float16 f16x2 __attribute__((ext_vector_type(2)));
typedef _Float16 half8 __attribute__((ext_vector_type(8)));
typedef float floatx4 __attribute__((ext_vector_type(4)));

__device__ __forceinline__ float2 unpack2(unsigned u) {
    __half2 h = *reinterpret_cast<__half2*>(&u);
    return __half22float2(h);
}
__device__ __forceinline__ unsigned f2h2(float lo, float hi) {
    __half2 h = __floats2half2_rn(lo, hi);
    return *reinterpret_cast<unsigned*>(&h);
}

#if defined(__has_builtin)
#if __has_builtin(__builtin_amdgcn_fdot2)
#define HAS_FDOT2 1
#endif
#if __has_builtin(__builtin_amdgcn_mfma_f32_16x16x32_f16)
#define HAS_MFMA 1
#endif
#endif
#ifndef HAS_FDOT2
#define HAS_FDOT2 0
#endif
#ifndef HAS_MFMA
#define HAS_MFMA 0
#endif

__device__ __forceinline__ float fdot2u(unsigned a, unsigned b, float c) {
#if HAS_FDOT2
    return __builtin_amdgcn_fdot2(__builtin_bit_cast(f16x2, a),
                                  __builtin_bit_cast(f16x2, b), c, false);
#else
    float2 fa = unpack2(a), fb = unpack2(b);
    return fmaf(fa.y, fb.y, fmaf(fa.x, fb.x, c));
#endif
}

// ---- pass 1a: per-chunk bucket histograms (bucket-major layout) ----
__global__ __launch_bounds__(256) void hist_chunks(const int* __restrict__ dst,
                                                   int* __restrict__ hist,
                                                   int E, int nbuck, int nchunk) {
    __shared__ int cnt[512];
    for (int i = threadIdx.x; i < nbuck; i += 256) cnt[i] = 0;
    __syncthreads();
    const int base = blockIdx.x * CHUNK;
    const int lim = min(base + CHUNK, E);
    for (int e = base + threadIdx.x; e < lim; e += 256)
        atomicAdd(&cnt[dst[e] >> 8], 1);
    __syncthreads();
    for (int b = threadIdx.x; b < nbuck; b += 256)
        hist[b * nchunk + blockIdx.x] = cnt[b];
}

// ---- hierarchical exclusive prefix sum (1024 elems/block) ----
__global__ __launch_bounds__(256) void scan_blocks(const int* __restrict__ in,
                                                   int* __restrict__ pre,
                                                   int* __restrict__ bsum, int m) {
    __shared__ int lds[256];
    const int t = threadIdx.x;
    const int base = blockIdx.x * 1024 + t * 4;
    int v0 = (base + 0 < m) ? in[base + 0] : 0;
    int v1 = (base + 1 < m) ? in[base + 1] : 0;
    int v2 = (base + 2 < m) ? in[base + 2] : 0;
    int v3 = (base + 3 < m) ? in[base + 3] : 0;
    int s = v0 + v1 + v2 + v3;
    lds[t] = s;
    __syncthreads();
    for (int off = 1; off < 256; off <<= 1) {
        int add = (t >= off) ? lds[t - off] : 0;
        __syncthreads();
        lds[t] += add;
        __syncthreads();
    }
    int e = lds[t] - s;
    if (base + 0 < m) pre[base + 0] = e;
    e += v0;
    if (base + 1 < m) pre[base + 1] = e;
    e += v1;
    if (base + 2 < m) pre[base + 2] = e;
    e += v2;
    if (base + 3 < m) pre[base + 3] = e;
    if (t == 255) bsum[blockIdx.x] = lds[255];
}

// scan of block sums + sentinel-row zeroing (folded init_sentinel)
__global__ __launch_bounds__(256) void scan_bsums(const int* __restrict__ bsum,
                                                  int* __restrict__ boffs, int nb,
                                                  unsigned* __restrict__ hs,
                                                  unsigned* __restrict__ hs2, int n) {
    __shared__ int lds[256];
    const int t = threadIdx.x;
    int v = (t < nb) ? bsum[t] : 0;
    lds[t] = v;
    __syncthreads();
    for (int off = 1; off < 256; off <<= 1) {
        int add = (t >= off) ? lds[t - off] : 0;
        __syncthreads();
        lds[t] += add;
        __syncthreads();
    }
    boffs[t] = lds[t] - v;
    if (t < 32) {
        hs[(size_t)n * 32 + t] = 0u;
        hs2[(size_t)n * 32 + t] = 0u;
    }
}

// ---- pass 1b: partition edges into bucket-grouped runs, 4B records ----
__global__ __launch_bounds__(256) void partition(const int* __restrict__ src,
                                                 const int* __restrict__ dst,
                                                 const int* __restrict__ offs,
                                                 const int* __restrict__ boffs,
                                                 unsigned* __restrict__ part,
                                                 int E, int nbuck, int nchunk) {
    __shared__ int off[512];
    for (int b = threadIdx.x; b < nbuck; b += 256) {
        int idx = b * nchunk + blockIdx.x;
        off[b] = offs[idx] + boffs[idx >> 10];
    }
    __syncthreads();
    const int base = blockIdx.x * CHUNK;
    const int lim = min(base + CHUNK, E);
    for (int e = base + threadIdx.x; e < lim; e += 256) {
        int d = dst[e], s = src[e];
        int pos = atomicAdd(&off[d >> 8], 1);
        part[pos] = ((unsigned)s << 8) | (unsigned)(d & 255);
    }
}

// ---- pass 2: per-bucket padded CSR finalize ----
// Row length padded to %16, sentinel src=n (zero row).  Bucket b's padded
// region starts at align128(bstart + b*4096) (max pad 256*15+31 < 4096).
__global__ __launch_bounds__(256) void build_bucket(const unsigned* __restrict__ part,
                                                    const int* __restrict__ offs,
                                                    const int* __restrict__ boffs,
                                                    int* __restrict__ csr_src,
                                                    int4* __restrict__ nodetab,
                                                    float* __restrict__ dinv,
                                                    int n, int E, int nbuck, int nchunk) {
    __shared__ int cnt[256], sc[256], off[256];
    __shared__ int stage[MAXB];
    const int b = blockIdx.x;
    const int t = threadIdx.x;
    const int i0 = b * nchunk;
    const int bstart = offs[i0] + boffs[i0 >> 10];
    int bend = E;
    if (b + 1 < nbuck) {
        const int i1 = (b + 1) * nchunk;
        bend = offs[i1] + boffs[i1 >> 10];
    }
    const int bstart_pad = (bstart + b * 4096 + 31) & ~31;   // 128B-aligned
    const int nodebase = b << 8;
    const int nnodes = min(256, n - nodebase);

    cnt[t] = 0;
    __syncthreads();
    for (int i = bstart + t; i < bend; i += 256)
        atomicAdd(&cnt[part[i] & 255u], 1);
    __syncthreads();
    const int deg = cnt[t];
    const int pdeg = (deg + 15) & ~15;
    sc[t] = pdeg;
    __syncthreads();
    for (int o = 1; o < 256; o <<= 1) {
        int add = (t >= o) ? sc[t - o] : 0;
        __syncthreads();
        sc[t] += add;
        __syncthreads();
    }
    const int pexcl = sc[t] - pdeg;
    const int psize = sc[255];
    if (t < nnodes) {
        float dv = rsqrtf((float)(deg + 1));   // +1 self loop
        nodetab[nodebase + t] = make_int4(bstart_pad + pexcl,
                                          bstart_pad + pexcl + pdeg,
                                          __float_as_int(dv), 0);
        dinv[nodebase + t] = dv;
    }
    off[t] = pexcl;
    __syncthreads();

    if (psize <= MAXB) {
        for (int i = t; i < psize; i += 256) stage[i] = n;   // sentinel fill
        __syncthreads();
        for (int i = bstart + t; i < bend; i += 256) {
            unsigned r = part[i];
            int pos = atomicAdd(&off[r & 255u], 1);
            stage[pos] = (int)(r >> 8);
        }
        __syncthreads();
        for (int i = t; i < psize; i += 256)
            csr_src[bstart_pad + i] = stage[i];
    } else {   // safety fallback
        for (int i = t; i < psize; i += 256) csr_src[bstart_pad + i] = n;
        __syncthreads();
        for (int i = bstart + t; i < bend; i += 256) {
            unsigned r = part[i];
            int pos = atomicAdd(&off[r & 255u], 1);
            csr_src[bstart_pad + pos] = (int)(r >> 8);
        }
    }
}

// hs[row] = fp16x2( dinv[row] * (x[row] @ W1) ).  MFMA (R13, HW-verified).
__global__ __launch_bounds__(256) void gemm1(const float* __restrict__ x,
                                             const float* __restrict__ W1,
                                             const float* __restrict__ dinv,
                                             unsigned* __restrict__ hs, int n) {
#if HAS_MFMA
    const int lane = threadIdx.x & 63;
    const int wave = threadIdx.x >> 6;
    const int q4 = lane >> 4;
    const int l16 = lane & 15;
    half8 bfrag[4][4];
#pragma unroll
    for (int ks = 0; ks < 4; ++ks)
#pragma unroll
        for (int cb = 0; cb < 4; ++cb)
#pragma unroll
            for (int j = 0; j < 8; ++j)
                bfrag[ks][cb][j] =
                    (_Float16)W1[(ks * 32 + q4 * 8 + j) * HID_F + cb * 16 + l16];

    const int ntile = (n + 15) >> 4;
    for (int t = blockIdx.x * 4 + wave; t < ntile; t += gridDim.x * 4) {
        const int r0 = t << 4;
        const int arow = min(r0 + l16, n - 1);
        const float* xr = x + (size_t)arow * IN_F + q4 * 8;
        half8 afrag[4];
#pragma unroll
        for (int ks = 0; ks < 4; ++ks) {
            float4 v0 = *(const float4*)(xr + ks * 32);
            float4 v1 = *(const float4*)(xr + ks * 32 + 4);
            half8 a;
            a[0] = (_Float16)v0.x; a[1] = (_Float16)v0.y;
            a[2] = (_Float16)v0.z; a[3] = (_Float16)v0.w;
            a[4] = (_Float16)v1.x; a[5] = (_Float16)v1.y;
            a[6] = (_Float16)v1.z; a[7] = (_Float16)v1.w;
            afrag[ks] = a;
        }
        floatx4 acc[4] = {{0.f,0.f,0.f,0.f},{0.f,0.f,0.f,0.f},
                          {0.f,0.f,0.f,0.f},{0.f,0.f,0.f,0.f}};
#pragma unroll
        for (int ks = 0; ks < 4; ++ks) {
#pragma unroll
            for (int cb = 0; cb < 4; ++cb)
                acc[cb] = __builtin_amdgcn_mfma_f32_16x16x32_f16(
                    afrag[ks], bfrag[ks][cb], acc[cb], 0, 0, 0);
        }
        const int rbase = r0 + q4 * 4;
        float4 dvv = *(const float4*)(dinv + rbase);
        float dvr[4] = {dvv.x, dvv.y, dvv.z, dvv.w};
#pragma unroll
        for (int cb = 0; cb < 4; ++cb) {
#pragma unroll
            for (int reg = 0; reg < 4; ++reg) {
                float v = acc[cb][reg] * dvr[reg];
                float o = __shfl_xor(v, 1);
                if (!(l16 & 1)) {
                    int r = rbase + reg;
                    if (r < n)
                        hs[(size_t)r * 32 + cb * 8 + (l16 >> 1)] = f2h2(v, o);
                }
            }
        }
    }
#endif
}

// Grid-stride; each wave owns TWO consecutive nodes, interleaved branchless
// chains.  8-lane row groups: slot g=lane>>3 owns edges (2g,2g+1) per
// 16-edge block via one int2 idx load; lane w=lane&7 holds feats 8w..8w+7
// as uint4 -> one gather instr = 8 distinct rows.  Rows padded %16.
#define ACC2(u, slo, shi) { slo = fdot2u(u, ONE_LO, slo); shi = fdot2u(u, ONE_HI, shi); }
template <int LAYER>
__global__ __launch_bounds__(256) void csr_agg(const int4* __restrict__ nodetab,
                                               const int* __restrict__ csr_src,
                                               const unsigned* __restrict__ hs,
                                               const float* __restrict__ bias,
                                               unsigned* __restrict__ hout, int n) {
    const int lane = threadIdx.x & 63;
    const int g = lane >> 3;          // edge slot 0..7
    const int w = lane & 7;           // feats 8w..8w+7 (uint4 #w of row)
    const uint4* __restrict__ hw4 = (const uint4*)hs + w;   // row = 8 uint4
    const int STR = gridDim.x * 8;
    const int SENT = n;

    int nodeA = (blockIdx.x * 4 + (threadIdx.x >> 6)) * 2;
    if (nodeA >= n) return;
    int4 ntA = nodetab[nodeA];
    bool hasB = nodeA + 1 < n;
    int4 ntB = hasB ? nodetab[nodeA + 1] : make_int4(0, 0, 0, 0);

    for (;;) {
        const int nxt = nodeA + STR;
        const bool more = nxt < n;
        int4 ntA_n, ntB_n;
        bool hasB_n = false;
        if (more) {
            ntA_n = nodetab[nxt];
            hasB_n = nxt + 1 < n;
            if (hasB_n) ntB_n = nodetab[nxt + 1];
        }

        int pA = ntA.x;
        const int endA = ntA.y;
        const float dnA = __int_as_float(ntA.z);
        int pB = hasB ? ntB.x : 0;
        const int endB = hasB ? ntB.y : 0;
        const float dnB = hasB ? __int_as_float(ntB.z) : 0.f;

        float aA0 = 0.f, aA1 = 0.f, aA2 = 0.f, aA3 = 0.f;
        float aA4 = 0.f, aA5 = 0.f, aA6 = 0.f, aA7 = 0.f;
        float aB0 = 0.f, aB1 = 0.f, aB2 = 0.f, aB3 = 0.f;
        float aB4 = 0.f, aB5 = 0.f, aB6 = 0.f, aB7 = 0.f;
        if (g == 0) {                                      // self loops, once
            uint4 suA = hw4[(size_t)nodeA * 8];
            ACC2(suA.x, aA0, aA1); ACC2(suA.y, aA2, aA3);
            ACC2(suA.z, aA4, aA5); ACC2(suA.w, aA6, aA7);
            if (hasB) {
                uint4 suB = hw4[(size_t)(nodeA + 1) * 8];
                ACC2(suB.x, aB0, aB1); ACC2(suB.y, aB2, aB3);
                ACC2(suB.z, aB4, aB5); ACC2(suB.w, aB6, aB7);
            }
        }
        while (pA < endA || pB < endB) {
            int2 ivA = (pA < endA) ? *(const int2*)&csr_src[pA + 2 * g]
                                   : make_int2(SENT, SENT);
            int2 ivB = (pB < endB) ? *(const int2*)&csr_src[pB + 2 * g]
                                   : make_int2(SENT, SENT);
            uint4 uA0 = hw4[(size_t)ivA.x * 8];
            uint4 uA1 = hw4[(size_t)ivA.y * 8];
            uint4 uB0 = hw4[(size_t)ivB.x * 8];
            uint4 uB1 = hw4[(size_t)ivB.y * 8];
            ACC2(uA0.x, aA0, aA1); ACC2(uA0.y, aA2, aA3);
            ACC2(uA0.z, aA4, aA5); ACC2(uA0.w, aA6, aA7);
            ACC2(uA1.x, aA0, aA1); ACC2(uA1.y, aA2, aA3);
            ACC2(uA1.z, aA4, aA5); ACC2(uA1.w, aA6, aA7);
            ACC2(uB0.x, aB0, aB1); ACC2(uB0.y, aB2, aB3);
            ACC2(uB0.z, aB4, aB5); ACC2(uB0.w, aB6, aB7);
            ACC2(uB1.x, aB0, aB1); ACC2(uB1.y, aB2, aB3);
            ACC2(uB1.z, aB4, aB5); ACC2(uB1.w, aB6, aB7);
            pA += 16; pB += 16;
        }
        // reduce across the 8 slots (lanes with same w, xor 8/16/32)
        aA0 += __shfl_xor(aA0, 8); aA0 += __shfl_xor(aA0, 16); aA0 += __shfl_xor(aA0, 32);
        aA1 += __shfl_xor(aA1, 8); aA1 += __shfl_xor(aA1, 16); aA1 += __shfl_xor(aA1, 32);
        aA2 += __shfl_xor(aA2, 8); aA2 += __shfl_xor(aA2, 16); aA2 += __shfl_xor(aA2, 32);
        aA3 += __shfl_xor(aA3, 8); aA3 += __shfl_xor(aA3, 16); aA3 += __shfl_xor(aA3, 32);
        aA4 += __shfl_xor(aA4, 8); aA4 += __shfl_xor(aA4, 16); aA4 += __shfl_xor(aA4, 32);
        aA5 += __shfl_xor(aA5, 8); aA5 += __shfl_xor(aA5, 16); aA5 += __shfl_xor(aA5, 32);
        aA6 += __shfl_xor(aA6, 8); aA6 += __shfl_xor(aA6, 16); aA6 += __shfl_xor(aA6, 32);
        aA7 += __shfl_xor(aA7, 8); aA7 += __shfl_xor(aA7, 16); aA7 += __shfl_xor(aA7, 32);
        aB0 += __shfl_xor(aB0, 8); aB0 += __shfl_xor(aB0, 16); aB0 += __shfl_xor(aB0, 32);
        aB1 += __shfl_xor(aB1, 8); aB1 += __shfl_xor(aB1, 16); aB1 += __shfl_xor(aB1, 32);
        aB2 += __shfl_xor(aB2, 8); aB2 += __shfl_xor(aB2, 16); aB2 += __shfl_xor(aB2, 32);
        aB3 += __shfl_xor(aB3, 8); aB3 += __shfl_xor(aB3, 16); aB3 += __shfl_xor(aB3, 32);
        aB4 += __shfl_xor(aB4, 8); aB4 += __shfl_xor(aB4, 16); aB4 += __shfl_xor(aB4, 32);
        aB5 += __shfl_xor(aB5, 8); aB5 += __shfl_xor(aB5, 16); aB5 += __shfl_xor(aB5, 32);
        aB6 += __shfl_xor(aB6, 8); aB6 += __shfl_xor(aB6, 16); aB6 += __shfl_xor(aB6, 32);
        aB7 += __shfl_xor(aB7, 8); aB7 += __shfl_xor(aB7, 16); aB7 += __shfl_xor(aB7, 32);

        if (g == 0) {
            float4 bb0, bb1;
            if (LAYER == 1) {
                bb0 = *(const float4*)(bias + 8 * w);
                bb1 = *(const float4*)(bias + 8 * w + 4);
            }
            float o0, o1, o2, o3, o4, o5, o6, o7;
            if (LAYER == 1) {
                o0 = fmaxf(fmaf(dnA, aA0, bb0.x), 0.f) * dnA;
                o1 = fmaxf(fmaf(dnA, aA1, bb0.y), 0.f) * dnA;
                o2 = fmaxf(fmaf(dnA, aA2, bb0.z), 0.f) * dnA;
                o3 = fmaxf(fmaf(dnA, aA3, bb0.w), 0.f) * dnA;
                o4 = fmaxf(fmaf(dnA, aA4, bb1.x), 0.f) * dnA;
                o5 = fmaxf(fmaf(dnA, aA5, bb1.y), 0.f) * dnA;
                o6 = fmaxf(fmaf(dnA, aA6, bb1.z), 0.f) * dnA;
                o7 = fmaxf(fmaf(dnA, aA7, bb1.w), 0.f) * dnA;
            } else {
                o0 = dnA * aA0; o1 = dnA * aA1; o2 = dnA * aA2; o3 = dnA * aA3;
                o4 = dnA * aA4; o5 = dnA * aA5; o6 = dnA * aA6; o7 = dnA * aA7;
            }
            uint4 ov;
            ov.x = f2h2(o0, o1); ov.y = f2h2(o2, o3);
            ov.z = f2h2(o4, o5); ov.w = f2h2(o6, o7);
            *(uint4*)(hout + (size_t)nodeA * 32 + 4 * w) = ov;
            if (hasB) {
                if (LAYER == 1) {
                    o0 = fmaxf(fmaf(dnB, aB0, bb0.x), 0.f) * dnB;
                    o1 = fmaxf(fmaf(dnB, aB1, bb0.y), 0.f) * dnB;
                    o2 = fmaxf(fmaf(dnB, aB2, bb0.z), 0.f) * dnB;
                    o3 = fmaxf(fmaf(dnB, aB3, bb0.w), 0.f) * dnB;
                    o4 = fmaxf(fmaf(dnB, aB4, bb1.x), 0.f) * dnB;
                    o5 = fmaxf(fmaf(dnB, aB5, bb1.y), 0.f) * dnB;
                    o6 = fmaxf(fmaf(dnB, aB6, bb1.z), 0.f) * dnB;
                    o7 = fmaxf(fmaf(dnB, aB7, bb1.w), 0.f) * dnB;
                } else {
                    o0 = dnB * aB0; o1 = dnB * aB1; o2 = dnB * aB2; o3 = dnB * aB3;
                    o4 = dnB * aB4; o5 = dnB * aB5; o6 = dnB * aB6; o7 = dnB * aB7;
                }
                ov.x = f2h2(o0, o1); ov.y = f2h2(o2, o3);
                ov.z = f2h2(o4, o5); ov.w = f2h2(o6, o7);
                *(uint4*)(hout + (size_t)(nodeA + 1) * 32 + 4 * w) = ov;
            }
        }
        if (!more) break;
        nodeA = nxt;
        ntA = ntA_n;
        hasB = hasB_n;
        ntB = ntB_n;
    }
}

// out[n][96] = a2[n][64] @ W2[64][96] + b2.  MFMA (R14, HW-verified).
__global__ __launch_bounds__(256) void gemm2(const unsigned* __restrict__ a2h,
                                             const float* __restrict__ W2,
                                             const float* __restrict__ b2,
                                             float* __restrict__ out, int n) {
#if HAS_MFMA
    const int lane = threadIdx.x & 63;
    const int wave = threadIdx.x >> 6;
    const int q4 = lane >> 4;
    const int l16 = lane & 15;
    half8 bfrag[2][6];
#pragma unroll
    for (int ks = 0; ks < 2; ++ks)
#pragma unroll
        for (int cb = 0; cb < 6; ++cb)
#pragma unroll
            for (int j = 0; j < 8; ++j)
                bfrag[ks][cb][j] =
                    (_Float16)W2[(ks * 32 + q4 * 8 + j) * OUT_F + cb * 16 + l16];
    float bb[6];
#pragma unroll
    for (int cb = 0; cb < 6; ++cb) bb[cb] = b2[cb * 16 + l16];

    const int ntile = (n + 15) >> 4;
    for (int t = blockIdx.x * 4 + wave; t < ntile; t += gridDim.x * 4) {
        const int r0 = t << 4;
        const int arow = min(r0 + l16, n - 1);
        const unsigned* ar = a2h + (size_t)arow * 32;
        half8 afrag[2];
#pragma unroll
        for (int ks = 0; ks < 2; ++ks) {
            uint4 v = *(const uint4*)(ar + ks * 16 + q4 * 4);
            afrag[ks] = __builtin_bit_cast(half8, v);
        }
        floatx4 acc[6] = {{0.f,0.f,0.f,0.f},{0.f,0.f,0.f,0.f},{0.f,0.f,0.f,0.f},
                          {0.f,0.f,0.f,0.f},{0.f,0.f,0.f,0.f},{0.f,0.f,0.f,0.f}};
#pragma unroll
        for (int ks = 0; ks < 2; ++ks) {
#pragma unroll
            for (int cb = 0; cb < 6; ++cb)
                acc[cb] = __builtin_amdgcn_mfma_f32_16x16x32_f16(
                    afrag[ks], bfrag[ks][cb], acc[cb], 0, 0, 0);
        }
        const int rbase = r0 + q4 * 4;
#pragma unroll
        for (int reg = 0; reg < 4; ++reg) {
            int r = rbase + reg;
            if (r < n) {
#pragma unroll
                for (int cb = 0; cb < 6; ++cb)
                    out[(size_t)r * OUT_F + cb * 16 + l16] = acc[cb][reg] + bb[cb];
            }
        }
    }
#endif
}

extern "C" void kernel_launch(void* const* d_in, const int* in_sizes, int n_in,
                              void* d_out, int out_size, void* d_ws, size_t ws_size,
                              hipStream_t stream) {
    const float* x  = (const float*)d_in[0];
    const int*   ei = (const int*)d_in[1];
    const float* W1 = (const float*)d_in[2];
    const float* b1 = (const float*)d_in[3];
    const float* W2 = (const float*)d_in[4];
    const float* b2 = (const float*)d_in[5];
    float* out = (float*)d_out;

    const int n = in_sizes[0] / IN_F;          // 100000
    const int E = in_sizes[1] / 2;             // 1600000
    const int* src = ei;
    const int* dst = ei + E;
    const int nbuck  = (n + 255) >> 8;         // 391
    const int nchunk = (E + CHUNK - 1) / CHUNK;// 391
    const int M = nbuck * nchunk;              // 152881
    const int NBS = (M + 1023) / 1024;
    const int g1tiles = (n + 15) / 16;         // 6250
    const int g1blocks = (g1tiles + 7) / 8;    // 782

    char* ws = (char*)d_ws;
    size_t off = 0;
    auto alloc = [&](size_t bytes) { void* p = ws + off; off = (off + bytes + 255) & ~(size_t)255; return p; };
    int*      hist    = (int*)alloc((size_t)M * 4);
    int*      offs    = (int*)alloc((size_t)M * 4);
    int*      bsum    = (int*)alloc(256 * 4);
    int*      boffs   = (int*)alloc(256 * 4);
    unsigned* part    = (unsigned*)alloc((size_t)E * 4);
    int*      csr_src = (int*)alloc(((size_t)E + (size_t)nbuck * 4096 + 128) * 4);
    int4*     nodetab = (int4*)alloc((size_t)n * 16);
    float*    dinv    = (float*)alloc((size_t)n * 4);
    unsigned* hs      = (unsigned*)alloc((size_t)(n + 1) * 32 * 4);
    unsigned* hs2     = (unsigned*)alloc((size_t)(n + 1) * 32 * 4);
    unsigned* a2h     = (unsigned*)alloc((size_t)n * 32 * 4);

    // CSR build: histogram -> scan (+sentinel init) -> partition -> finalize
    hist_chunks <<<nchunk, 256, 0, stream>>>(dst, hist, E, nbuck, nchunk);
    scan_blocks <<<NBS, 256, 0, stream>>>(hist, offs, bsum, M);
    scan_bsums  <<<1, 256, 0, stream>>>(bsum, boffs, NBS, hs, hs2, n);
    partition   <<<nchunk, 256, 0, stream>>>(src, dst, offs, boffs, part, E, nbuck, nchunk);
    build_bucket<<<nbuck, 256, 0, stream>>>(part, offs, boffs, csr_src, nodetab, dinv,
                                            n, E, nbuck, nchunk);

    // network
    gemm1      <<<g1blocks, 256, 0, stream>>>(x, W1, dinv, hs, n);
    csr_agg<1> <<<AGG_BLOCKS, 256, 0, stream>>>(nodetab, csr_src, hs, b1, hs2, n);
    csr_agg<2> <<<AGG_BLOCKS, 256, 0, stream>>>(nodetab, csr_src, hs2, NULL, a2h, n);
    gemm2      <<<g1blocks, 256, 0, stream>>>(a2h, W2, b2, out, n);
}